// Round 1
// baseline (1122.184 us; speedup 1.0000x reference)
//
#include <hip/hip_runtime.h>
#include <cstddef>

#define EPS 1e-5f

// ---------------- degree / norm ----------------
__global__ void deg_kernel(const int* __restrict__ dst, int E, float* __restrict__ deg) {
    int i = blockIdx.x * blockDim.x + threadIdx.x;
    if (i < E) atomicAdd(&deg[dst[i]], 1.0f);
}

__global__ void dinv_kernel(const float* __restrict__ deg, float* __restrict__ dinv, int n) {
    int i = blockIdx.x * blockDim.x + threadIdx.x;
    if (i < n) dinv[i] = rsqrtf(deg[i] + 1.0f);  // +1 = self loop
}

// ---------------- GEMM: out[n,C] = h[n,K] @ W[K,C], W row-major ----------------
template <int K, int C, int RPB>
__global__ __launch_bounds__(C) void gemm_kernel(const float* __restrict__ h,
                                                 const float* __restrict__ W,
                                                 float* __restrict__ out, int n) {
    __shared__ float Ws[K * C];
    __shared__ float hrow[RPB * K];
    for (int i = threadIdx.x; i < K * C; i += C) Ws[i] = W[i];
    __syncthreads();
    int c = threadIdx.x;
    for (int r0 = blockIdx.x * RPB; r0 < n; r0 += gridDim.x * RPB) {
        int nr = (n - r0 < RPB) ? (n - r0) : RPB;
        for (int i = threadIdx.x; i < nr * K; i += C)
            hrow[i] = h[(size_t)r0 * K + i];
        __syncthreads();
        float acc[RPB];
#pragma unroll
        for (int j = 0; j < RPB; j++) acc[j] = 0.0f;
        for (int k = 0; k < K; k++) {
            float w = Ws[k * C + c];
#pragma unroll
            for (int j = 0; j < RPB; j++) acc[j] = fmaf(hrow[j * K + k], w, acc[j]);
        }
        for (int j = 0; j < nr; j++) out[(size_t)(r0 + j) * C + c] = acc[j];
        __syncthreads();
    }
}

// GEMV: out[n] = h[n,128] @ W[128]  (one wave per row)
__global__ void gemv_kernel(const float* __restrict__ h, const float* __restrict__ W,
                            float* __restrict__ out, int n) {
    int gid = blockIdx.x * blockDim.x + threadIdx.x;
    int wid = gid >> 6, lane = gid & 63;
    int nw = (gridDim.x * blockDim.x) >> 6;
    float w0 = W[lane], w1 = W[64 + lane];
    for (int r = wid; r < n; r += nw) {
        const float* hr = h + (size_t)r * 128;
        float v = fmaf(hr[lane], w0, hr[64 + lane] * w1);
#pragma unroll
        for (int off = 32; off > 0; off >>= 1) v += __shfl_down(v, off, 64);
        if (lane == 0) out[r] = v;
    }
}

// ---------------- edge scatter ----------------
__global__ void scatter128_kernel(const float* __restrict__ tmp, const int* __restrict__ src,
                                  const int* __restrict__ dst, const float* __restrict__ dinv,
                                  float* __restrict__ agg, int E) {
    int c = threadIdx.x & 127;
    int eo = threadIdx.x >> 7;
    for (int e = blockIdx.x * 2 + eo; e < E; e += gridDim.x * 2) {
        int s = src[e], d = dst[e];
        float nrm = dinv[s] * dinv[d];
        float v = tmp[(size_t)s * 128 + c] * nrm;
        atomicAdd(&agg[(size_t)d * 128 + c], v);
    }
}

__global__ void scatter1_kernel(const float* __restrict__ tmp, const int* __restrict__ src,
                                const int* __restrict__ dst, const float* __restrict__ dinv,
                                float* __restrict__ agg, int E) {
    int e = blockIdx.x * blockDim.x + threadIdx.x;
    if (e < E) {
        int s = src[e], d = dst[e];
        atomicAdd(&agg[d], tmp[s] * dinv[s] * dinv[d]);
    }
}

__global__ void selfloop128_kernel(const float* __restrict__ tmp, const float* __restrict__ dinv,
                                   float* __restrict__ agg, int n) {
    int i = blockIdx.x * blockDim.x + threadIdx.x;
    if (i < n * 128) {
        float di = dinv[i >> 7];
        agg[i] += tmp[i] * di * di;
    }
}

__global__ void selfloop1_kernel(const float* __restrict__ tmp, const float* __restrict__ dinv,
                                 float* __restrict__ agg, int n) {
    int i = blockIdx.x * blockDim.x + threadIdx.x;
    if (i < n) {
        float di = dinv[i];
        agg[i] += tmp[i] * di * di;
    }
}

// ---------------- stats: sums[c]=sum, sums[C+c]=sumsq ----------------
__global__ __launch_bounds__(128) void stats128_kernel(const float* __restrict__ a,
                                                       float* __restrict__ sums, int n) {
    int t = threadIdx.x;
    float s = 0.f, q = 0.f;
    for (int r = blockIdx.x; r < n; r += gridDim.x) {
        float v = a[(size_t)r * 128 + t];
        s += v;
        q += v * v;
    }
    atomicAdd(&sums[t], s);
    atomicAdd(&sums[128 + t], q);
}

__global__ void stats1_kernel(const float* __restrict__ a, float* __restrict__ sums, int n) {
    int gid = blockIdx.x * blockDim.x + threadIdx.x;
    float s = 0.f, q = 0.f;
    for (int i = gid; i < n; i += gridDim.x * blockDim.x) {
        float v = a[i];
        s += v;
        q += v * v;
    }
#pragma unroll
    for (int off = 32; off > 0; off >>= 1) {
        s += __shfl_down(s, off, 64);
        q += __shfl_down(q, off, 64);
    }
    if ((threadIdx.x & 63) == 0) {
        atomicAdd(&sums[0], s);
        atomicAdd(&sums[1], q);
    }
}

// ---------------- finalize: fused BN->IN->LN scale/shift per channel ----------------
// a = agg + b; BN subtracts mean(a) -> b cancels. IN subtracts bt -> bt cancels.
// u = (agg - m)*t, t = rsqrt(v+eps)*g*rsqrt(g^2*v/(v+eps)+eps)
// LN(graph): global mean(u)=0, global var = mean_c(v_c t_c^2)
// y = agg*S + (lb - m*S), S = t*rsqrt(GV+eps)*lw
template <int C>
__global__ void finalize_kernel(const float* __restrict__ sums, const float* __restrict__ g,
                                const float* __restrict__ lw, const float* __restrict__ lb,
                                float* __restrict__ ss, int n) {
    __shared__ float vt2[C];
    int c = threadIdx.x;
    float m = sums[c] / n;
    float v = sums[C + c] / n - m * m;
    v = v < 0.f ? 0.f : v;
    float gc = g[c];
    float bs = rsqrtf(v + EPS) * gc;
    float vz = v * bs * bs;
    float t = bs * rsqrtf(vz + EPS);
    vt2[c] = v * t * t;
    __syncthreads();
    if (c == 0) {
        float gv = 0.f;
        for (int i = 0; i < C; i++) gv += vt2[i];
        vt2[0] = gv / C;
    }
    __syncthreads();
    float GV = vt2[0];
    float S = t * rsqrtf(GV + EPS) * lw[c];
    ss[c] = S;
    ss[C + c] = lb[c] - m * S;
}

// ---------------- apply (optionally in place) ----------------
template <int C, bool RELU>
__global__ void apply_kernel(const float* __restrict__ ss, const float* a, float* out, int n) {
    int i = blockIdx.x * blockDim.x + threadIdx.x;
    if (i < n * C) {
        int c = (C == 1) ? 0 : (i & (C - 1));
        float y = fmaf(a[i], ss[c], ss[C + c]);
        if (RELU) y = y > 0.f ? y : 0.f;
        out[i] = y;
    }
}

extern "C" void kernel_launch(void* const* d_in, const int* in_sizes, int n_in,
                              void* d_out, int out_size, void* d_ws, size_t ws_size,
                              hipStream_t stream) {
    const float* x = (const float*)d_in[0];
    const int* ei = (const int*)d_in[1];
    int n = in_sizes[0] / 32;
    int E = in_sizes[1] / 2;
    const int* src = ei;
    const int* dstp = ei + E;
    const float* W1 = (const float*)d_in[2];
    const float* g1 = (const float*)d_in[4];
    const float* lw1 = (const float*)d_in[6];
    const float* lb1 = (const float*)d_in[7];
    const float* W2 = (const float*)d_in[8];
    const float* g2 = (const float*)d_in[10];
    const float* lw2 = (const float*)d_in[12];
    const float* lb2 = (const float*)d_in[13];
    const float* W3 = (const float*)d_in[14];
    const float* g3 = (const float*)d_in[16];
    const float* lw3 = (const float*)d_in[18];
    const float* lb3 = (const float*)d_in[19];
    float* out = (float*)d_out;

    float* ws = (float*)d_ws;
    float* deg = ws;                          // n
    float* dinv = deg + n;                    // n
    float* buf0 = dinv + n;                   // n*128
    float* buf1 = buf0 + (size_t)n * 128;     // n*128
    float* buf2 = buf1 + (size_t)n * 128;     // n
    float* buf3 = buf2 + n;                   // n
    float* sums = buf3 + n;                   // 256
    float* ss = sums + 256;                   // 256

    // degrees -> dinv
    hipMemsetAsync(deg, 0, (size_t)n * sizeof(float), stream);
    deg_kernel<<<(E + 255) / 256, 256, 0, stream>>>(dstp, E, deg);
    dinv_kernel<<<(n + 255) / 256, 256, 0, stream>>>(deg, dinv, n);

    // ---- layer 1: 32 -> 128 ----
    gemm_kernel<32, 128, 4><<<1024, 128, 0, stream>>>(x, W1, buf0, n);
    hipMemsetAsync(buf1, 0, (size_t)n * 128 * sizeof(float), stream);
    scatter128_kernel<<<8192, 256, 0, stream>>>(buf0, src, dstp, dinv, buf1, E);
    selfloop128_kernel<<<(n * 128 + 255) / 256, 256, 0, stream>>>(buf0, dinv, buf1, n);
    hipMemsetAsync(sums, 0, 256 * sizeof(float), stream);
    stats128_kernel<<<256, 128, 0, stream>>>(buf1, sums, n);
    finalize_kernel<128><<<1, 128, 0, stream>>>(sums, g1, lw1, lb1, ss, n);
    apply_kernel<128, true><<<(n * 128 + 255) / 256, 256, 0, stream>>>(ss, buf1, buf1, n);

    // ---- layer 2: 128 -> 128 ----
    gemm_kernel<128, 128, 4><<<1024, 128, 0, stream>>>(buf1, W2, buf0, n);
    hipMemsetAsync(buf1, 0, (size_t)n * 128 * sizeof(float), stream);
    scatter128_kernel<<<8192, 256, 0, stream>>>(buf0, src, dstp, dinv, buf1, E);
    selfloop128_kernel<<<(n * 128 + 255) / 256, 256, 0, stream>>>(buf0, dinv, buf1, n);
    hipMemsetAsync(sums, 0, 256 * sizeof(float), stream);
    stats128_kernel<<<256, 128, 0, stream>>>(buf1, sums, n);
    finalize_kernel<128><<<1, 128, 0, stream>>>(sums, g2, lw2, lb2, ss, n);
    apply_kernel<128, true><<<(n * 128 + 255) / 256, 256, 0, stream>>>(ss, buf1, buf1, n);

    // ---- layer 3: 128 -> 1 ----
    gemv_kernel<<<1024, 256, 0, stream>>>(buf1, W3, buf2, n);
    hipMemsetAsync(buf3, 0, (size_t)n * sizeof(float), stream);
    scatter1_kernel<<<(E + 255) / 256, 256, 0, stream>>>(buf2, src, dstp, dinv, buf3, E);
    selfloop1_kernel<<<(n + 255) / 256, 256, 0, stream>>>(buf2, dinv, buf3, n);
    hipMemsetAsync(sums, 0, 2 * sizeof(float), stream);
    stats1_kernel<<<256, 256, 0, stream>>>(buf3, sums, n);
    finalize_kernel<1><<<1, 1, 0, stream>>>(sums, g3, lw3, lb3, ss, n);
    apply_kernel<1, false><<<(n + 255) / 256, 256, 0, stream>>>(ss, buf3, out, n);
}

// Round 2
// 871.452 us; speedup vs baseline: 1.2877x; 1.2877x over previous
//
#include <hip/hip_runtime.h>
#include <cstddef>

#define EPS 1e-5f

// ---------------- degree / norm ----------------
__global__ void deg_kernel(const int* __restrict__ dst, int E, float* __restrict__ deg) {
    int i = blockIdx.x * blockDim.x + threadIdx.x;
    if (i < E) atomicAdd(&deg[dst[i]], 1.0f);
}

__global__ void dinv_kernel(const float* __restrict__ deg, float* __restrict__ dinv, int n) {
    int i = blockIdx.x * blockDim.x + threadIdx.x;
    if (i < n) dinv[i] = rsqrtf(deg[i] + 1.0f);  // +1 = self loop
}

// ---------------- tiled GEMM: out[n,128] = norm(h[n,K]) @ W[K,128] ----------------
// 128x128 tile per block, 256 threads, 8x8 micro-tile per thread.
// NORM: input h is raw agg; apply y = relu(h*S[k]+T[k]) per input channel k on load.
template <int K, bool NORM>
__global__ __launch_bounds__(256) void gemm_tiled(const float* __restrict__ h,
                                                  const float* __restrict__ W,
                                                  const float* __restrict__ ss,
                                                  float* __restrict__ out, int n) {
    constexpr int KT = 16;
    __shared__ float hs[KT][128];  // transposed: hs[k][row]
    __shared__ float ws[KT][128];  // ws[k][col]
    int tid = threadIdx.x;
    int tx = tid & 15;   // col group: cols tx*8..tx*8+7
    int ty = tid >> 4;   // row group: rows ty*8..ty*8+7
    int r0 = blockIdx.x * 128;

    float acc[8][8];
#pragma unroll
    for (int i = 0; i < 8; i++)
#pragma unroll
        for (int j = 0; j < 8; j++) acc[i][j] = 0.0f;

    int srow = tid >> 1;            // staging row 0..127
    int skq = (tid & 1) * 8;        // staging k offset 0 or 8
    int gr = r0 + srow;

    for (int k0 = 0; k0 < K; k0 += KT) {
        // stage h tile (transposed into hs)
#pragma unroll
        for (int half = 0; half < 2; half++) {
            int kk = skq + half * 4;
            float4 v = make_float4(0.f, 0.f, 0.f, 0.f);
            if (gr < n) v = *(const float4*)(h + (size_t)gr * K + k0 + kk);
            if (NORM) {
                float4 s = *(const float4*)(ss + k0 + kk);
                float4 t = *(const float4*)(ss + K + k0 + kk);
                v.x = fmaxf(fmaf(v.x, s.x, t.x), 0.f);
                v.y = fmaxf(fmaf(v.y, s.y, t.y), 0.f);
                v.z = fmaxf(fmaf(v.z, s.z, t.z), 0.f);
                v.w = fmaxf(fmaf(v.w, s.w, t.w), 0.f);
            }
            hs[kk + 0][srow] = v.x;
            hs[kk + 1][srow] = v.y;
            hs[kk + 2][srow] = v.z;
            hs[kk + 3][srow] = v.w;
        }
        // stage W tile (direct)
#pragma unroll
        for (int j = 0; j < 2; j++) {
            int f = tid + j * 256;   // float4 index in [0,512)
            int kk = f >> 5;         // 32 float4 per row of 128
            int cc = (f & 31) * 4;
            *(float4*)&ws[kk][cc] = *(const float4*)(W + (size_t)(k0 + kk) * 128 + cc);
        }
        __syncthreads();
#pragma unroll
        for (int k = 0; k < KT; k++) {
            float a[8], b[8];
            *(float4*)&a[0] = *(float4*)&hs[k][ty * 8];
            *(float4*)&a[4] = *(float4*)&hs[k][ty * 8 + 4];
            *(float4*)&b[0] = *(float4*)&ws[k][tx * 8];
            *(float4*)&b[4] = *(float4*)&ws[k][tx * 8 + 4];
#pragma unroll
            for (int i = 0; i < 8; i++)
#pragma unroll
                for (int j = 0; j < 8; j++) acc[i][j] = fmaf(a[i], b[j], acc[i][j]);
        }
        __syncthreads();
    }
#pragma unroll
    for (int i = 0; i < 8; i++) {
        int r = r0 + ty * 8 + i;
        if (r < n) {
            *(float4*)(out + (size_t)r * 128 + tx * 8) =
                make_float4(acc[i][0], acc[i][1], acc[i][2], acc[i][3]);
            *(float4*)(out + (size_t)r * 128 + tx * 8 + 4) =
                make_float4(acc[i][4], acc[i][5], acc[i][6], acc[i][7]);
        }
    }
}

// GEMV with fused input norm: out[n] = relu(h[n,128]*S+T) @ W[128] (one wave per row)
__global__ void gemv_norm_kernel(const float* __restrict__ h, const float* __restrict__ W,
                                 const float* __restrict__ ss, float* __restrict__ out, int n) {
    int gid = blockIdx.x * blockDim.x + threadIdx.x;
    int wid = gid >> 6, lane = gid & 63;
    int nw = (gridDim.x * blockDim.x) >> 6;
    float w0 = W[lane], w1 = W[64 + lane];
    float s0 = ss[lane], s1 = ss[64 + lane];
    float t0 = ss[128 + lane], t1 = ss[192 + lane];
    for (int r = wid; r < n; r += nw) {
        const float* hr = h + (size_t)r * 128;
        float a = fmaxf(fmaf(hr[lane], s0, t0), 0.f);
        float b = fmaxf(fmaf(hr[64 + lane], s1, t1), 0.f);
        float v = fmaf(a, w0, b * w1);
#pragma unroll
        for (int off = 32; off > 0; off >>= 1) v += __shfl_down(v, off, 64);
        if (lane == 0) out[r] = v;
    }
}

// ---------------- edge scatter ----------------
__global__ void scatter128_kernel(const float* __restrict__ tmp, const int* __restrict__ src,
                                  const int* __restrict__ dst, const float* __restrict__ dinv,
                                  float* __restrict__ agg, int E) {
    int c = threadIdx.x & 127;
    int eo = threadIdx.x >> 7;
    for (int e = blockIdx.x * 2 + eo; e < E; e += gridDim.x * 2) {
        int s = src[e], d = dst[e];
        float nrm = dinv[s] * dinv[d];
        float v = tmp[(size_t)s * 128 + c] * nrm;
        atomicAdd(&agg[(size_t)d * 128 + c], v);
    }
}

__global__ void scatter1_kernel(const float* __restrict__ tmp, const int* __restrict__ src,
                                const int* __restrict__ dst, const float* __restrict__ dinv,
                                float* __restrict__ agg, int E) {
    int e = blockIdx.x * blockDim.x + threadIdx.x;
    if (e < E) {
        int s = src[e], d = dst[e];
        atomicAdd(&agg[d], tmp[s] * dinv[s] * dinv[d]);
    }
}

// selfloop init: agg = tmp * dinv^2  (replaces memset + add)
__global__ void selfloop_init128(const float* __restrict__ tmp, const float* __restrict__ dinv,
                                 float* __restrict__ agg, int n) {
    int i = blockIdx.x * blockDim.x + threadIdx.x;  // float4 index
    if (i < n * 32) {
        float di = dinv[i >> 5];
        float d2 = di * di;
        float4 v = ((const float4*)tmp)[i];
        v.x *= d2; v.y *= d2; v.z *= d2; v.w *= d2;
        ((float4*)agg)[i] = v;
    }
}

__global__ void selfloop_init1(const float* __restrict__ tmp, const float* __restrict__ dinv,
                               float* __restrict__ agg, int n) {
    int i = blockIdx.x * blockDim.x + threadIdx.x;
    if (i < n) {
        float di = dinv[i];
        agg[i] = tmp[i] * di * di;
    }
}

// ---------------- stats: sums[c]=sum, sums[C+c]=sumsq ----------------
__global__ __launch_bounds__(128) void stats128_kernel(const float* __restrict__ a,
                                                       float* __restrict__ sums, int n) {
    int t = threadIdx.x;
    float s = 0.f, q = 0.f;
    for (int r = blockIdx.x; r < n; r += gridDim.x) {
        float v = a[(size_t)r * 128 + t];
        s += v;
        q += v * v;
    }
    atomicAdd(&sums[t], s);
    atomicAdd(&sums[128 + t], q);
}

__global__ void stats1_kernel(const float* __restrict__ a, float* __restrict__ sums, int n) {
    int gid = blockIdx.x * blockDim.x + threadIdx.x;
    float s = 0.f, q = 0.f;
    for (int i = gid; i < n; i += gridDim.x * blockDim.x) {
        float v = a[i];
        s += v;
        q += v * v;
    }
#pragma unroll
    for (int off = 32; off > 0; off >>= 1) {
        s += __shfl_down(s, off, 64);
        q += __shfl_down(q, off, 64);
    }
    if ((threadIdx.x & 63) == 0) {
        atomicAdd(&sums[0], s);
        atomicAdd(&sums[1], q);
    }
}

// ---------------- finalize: fused BN->IN->LN scale/shift per channel ----------------
template <int C>
__global__ void finalize_kernel(const float* __restrict__ sums, const float* __restrict__ g,
                                const float* __restrict__ lw, const float* __restrict__ lb,
                                float* __restrict__ ss, int n) {
    __shared__ float vt2[C];
    int c = threadIdx.x;
    float m = sums[c] / n;
    float v = sums[C + c] / n - m * m;
    v = v < 0.f ? 0.f : v;
    float gc = g[c];
    float bs = rsqrtf(v + EPS) * gc;
    float vz = v * bs * bs;
    float t = bs * rsqrtf(vz + EPS);
    vt2[c] = v * t * t;
    __syncthreads();
    if (c == 0) {
        float gv = 0.f;
        for (int i = 0; i < C; i++) gv += vt2[i];
        vt2[0] = gv / C;
    }
    __syncthreads();
    float GV = vt2[0];
    float S = t * rsqrtf(GV + EPS) * lw[c];
    ss[c] = S;
    ss[C + c] = lb[c] - m * S;
}

template <int C, bool RELU>
__global__ void apply_kernel(const float* __restrict__ ss, const float* a, float* out, int n) {
    int i = blockIdx.x * blockDim.x + threadIdx.x;
    if (i < n * C) {
        int c = (C == 1) ? 0 : (i & (C - 1));
        float y = fmaf(a[i], ss[c], ss[C + c]);
        if (RELU) y = y > 0.f ? y : 0.f;
        out[i] = y;
    }
}

extern "C" void kernel_launch(void* const* d_in, const int* in_sizes, int n_in,
                              void* d_out, int out_size, void* d_ws, size_t ws_size,
                              hipStream_t stream) {
    const float* x = (const float*)d_in[0];
    const int* ei = (const int*)d_in[1];
    int n = in_sizes[0] / 32;
    int E = in_sizes[1] / 2;
    const int* src = ei;
    const int* dstp = ei + E;
    const float* W1 = (const float*)d_in[2];
    const float* g1 = (const float*)d_in[4];
    const float* lw1 = (const float*)d_in[6];
    const float* lb1 = (const float*)d_in[7];
    const float* W2 = (const float*)d_in[8];
    const float* g2 = (const float*)d_in[10];
    const float* lw2 = (const float*)d_in[12];
    const float* lb2 = (const float*)d_in[13];
    const float* W3 = (const float*)d_in[14];
    const float* g3 = (const float*)d_in[16];
    const float* lw3 = (const float*)d_in[18];
    const float* lb3 = (const float*)d_in[19];
    float* out = (float*)d_out;

    float* ws = (float*)d_ws;
    float* deg = ws;                        // n
    float* dinv = deg + n;                  // n
    float* buf0 = dinv + n;                 // n*128 (gemm out / scatter src)
    float* buf1 = buf0 + (size_t)n * 128;   // n*128 (agg)
    float* buf2 = buf1 + (size_t)n * 128;   // n
    float* buf3 = buf2 + n;                 // n
    float* sums1 = buf3 + n;                // 256
    float* sums2 = sums1 + 256;             // 256
    float* sums3 = sums2 + 256;             // 4 (pad)
    float* ss1 = sums3 + 4;                 // 256
    float* ss2 = ss1 + 256;                 // 256
    float* ss3 = ss2 + 256;                 // 4

    // zero all stats accumulators in one small memset (516 floats)
    hipMemsetAsync(sums1, 0, 516 * sizeof(float), stream);
    hipMemsetAsync(deg, 0, (size_t)n * sizeof(float), stream);
    deg_kernel<<<(E + 255) / 256, 256, 0, stream>>>(dstp, E, deg);
    dinv_kernel<<<(n + 255) / 256, 256, 0, stream>>>(deg, dinv, n);

    int gblk = (n + 127) / 128;

    // ---- layer 1: 32 -> 128 ----
    gemm_tiled<32, false><<<gblk, 256, 0, stream>>>(x, W1, nullptr, buf0, n);
    selfloop_init128<<<(n * 32 + 255) / 256, 256, 0, stream>>>(buf0, dinv, buf1, n);
    scatter128_kernel<<<8192, 256, 0, stream>>>(buf0, src, dstp, dinv, buf1, E);
    stats128_kernel<<<256, 128, 0, stream>>>(buf1, sums1, n);
    finalize_kernel<128><<<1, 128, 0, stream>>>(sums1, g1, lw1, lb1, ss1, n);

    // ---- layer 2: 128 -> 128 (input norm fused into gemm load) ----
    gemm_tiled<128, true><<<gblk, 256, 0, stream>>>(buf1, W2, ss1, buf0, n);
    selfloop_init128<<<(n * 32 + 255) / 256, 256, 0, stream>>>(buf0, dinv, buf1, n);
    scatter128_kernel<<<8192, 256, 0, stream>>>(buf0, src, dstp, dinv, buf1, E);
    stats128_kernel<<<256, 128, 0, stream>>>(buf1, sums2, n);
    finalize_kernel<128><<<1, 128, 0, stream>>>(sums2, g2, lw2, lb2, ss2, n);

    // ---- layer 3: 128 -> 1 (input norm fused into gemv) ----
    gemv_norm_kernel<<<1024, 256, 0, stream>>>(buf1, W3, ss2, buf2, n);
    selfloop_init1<<<(n + 255) / 256, 256, 0, stream>>>(buf2, dinv, buf3, n);
    scatter1_kernel<<<(E + 255) / 256, 256, 0, stream>>>(buf2, src, dstp, dinv, buf3, E);
    stats1_kernel<<<256, 256, 0, stream>>>(buf3, sums3, n);
    finalize_kernel<1><<<1, 1, 0, stream>>>(sums3, g3, lw3, lb3, ss3, n);
    apply_kernel<1, false><<<(n + 255) / 256, 256, 0, stream>>>(ss3, buf3, out, n);
}

// Round 3
// 580.590 us; speedup vs baseline: 1.9328x; 1.5010x over previous
//
#include <hip/hip_runtime.h>
#include <cstddef>

#define EPS 1e-5f

// ================= CSR build (by dst) =================
__global__ void hist_kernel(const int* __restrict__ dst, int E, int* __restrict__ counts) {
    int i = blockIdx.x * blockDim.x + threadIdx.x;
    if (i < E) atomicAdd(&counts[dst[i]], 1);
}

__global__ void dinv_kernel(const int* __restrict__ counts, float* __restrict__ dinv, int n) {
    int i = blockIdx.x * blockDim.x + threadIdx.x;
    if (i < n) dinv[i] = rsqrtf((float)counts[i] + 1.0f);  // +1 = self loop
}

// exclusive scan of counts -> rowptr, 1024 elems per block
__global__ __launch_bounds__(1024) void scan_part(const int* __restrict__ counts,
                                                  int* __restrict__ rowptr,
                                                  int* __restrict__ aux, int n) {
    __shared__ int sh[1024];
    int t = threadIdx.x;
    int g = blockIdx.x * 1024 + t;
    int v = (g < n) ? counts[g] : 0;
    sh[t] = v;
    __syncthreads();
    for (int off = 1; off < 1024; off <<= 1) {
        int add = (t >= off) ? sh[t - off] : 0;
        __syncthreads();
        sh[t] += add;
        __syncthreads();
    }
    if (g < n) rowptr[g] = sh[t] - v;  // exclusive
    if (t == 1023) aux[blockIdx.x] = sh[t];
}

__global__ __launch_bounds__(128) void scan_aux(int* __restrict__ aux, int B) {
    __shared__ int sh[128];
    int t = threadIdx.x;
    int v = (t < B) ? aux[t] : 0;
    sh[t] = v;
    __syncthreads();
    for (int off = 1; off < 128; off <<= 1) {
        int add = (t >= off) ? sh[t - off] : 0;
        __syncthreads();
        sh[t] += add;
        __syncthreads();
    }
    if (t < B) aux[t] = sh[t] - v;  // exclusive block offsets
}

__global__ void scan_add(int* __restrict__ rowptr, const int* __restrict__ aux, int n, int E) {
    int g = blockIdx.x * blockDim.x + threadIdx.x;
    if (g < n) rowptr[g] += aux[g >> 10];
    if (g == 0) rowptr[n] = E;
}

// cnt must be zeroed; writes src index per slot
__global__ void fill_kernel(const int* __restrict__ src, const int* __restrict__ dst, int E,
                            const int* __restrict__ rowptr, int* __restrict__ cnt,
                            int* __restrict__ esrc) {
    int e = blockIdx.x * blockDim.x + threadIdx.x;
    if (e < E) {
        int d = dst[e];
        int p = rowptr[d] + atomicAdd(&cnt[d], 1);
        esrc[p] = src[e];
    }
}

// ================= tiled GEMM: out[n,128] = norm(h[n,K]) @ W[K,128] =================
template <int K, bool NORM>
__global__ __launch_bounds__(256) void gemm_tiled(const float* __restrict__ h,
                                                  const float* __restrict__ W,
                                                  const float* __restrict__ ss,
                                                  float* __restrict__ out, int n) {
    constexpr int KT = 16;
    __shared__ float hs[KT][128];  // transposed: hs[k][row]
    __shared__ float ws[KT][128];  // ws[k][col]
    int tid = threadIdx.x;
    int tx = tid & 15;
    int ty = tid >> 4;
    int r0 = blockIdx.x * 128;

    float acc[8][8];
#pragma unroll
    for (int i = 0; i < 8; i++)
#pragma unroll
        for (int j = 0; j < 8; j++) acc[i][j] = 0.0f;

    int srow = tid >> 1;
    int skq = (tid & 1) * 8;
    int gr = r0 + srow;

    for (int k0 = 0; k0 < K; k0 += KT) {
#pragma unroll
        for (int half = 0; half < 2; half++) {
            int kk = skq + half * 4;
            float4 v = make_float4(0.f, 0.f, 0.f, 0.f);
            if (gr < n) v = *(const float4*)(h + (size_t)gr * K + k0 + kk);
            if (NORM) {
                float4 s = *(const float4*)(ss + k0 + kk);
                float4 t = *(const float4*)(ss + K + k0 + kk);
                v.x = fmaxf(fmaf(v.x, s.x, t.x), 0.f);
                v.y = fmaxf(fmaf(v.y, s.y, t.y), 0.f);
                v.z = fmaxf(fmaf(v.z, s.z, t.z), 0.f);
                v.w = fmaxf(fmaf(v.w, s.w, t.w), 0.f);
            }
            hs[kk + 0][srow] = v.x;
            hs[kk + 1][srow] = v.y;
            hs[kk + 2][srow] = v.z;
            hs[kk + 3][srow] = v.w;
        }
#pragma unroll
        for (int j = 0; j < 2; j++) {
            int f = tid + j * 256;
            int kk = f >> 5;
            int cc = (f & 31) * 4;
            *(float4*)&ws[kk][cc] = *(const float4*)(W + (size_t)(k0 + kk) * 128 + cc);
        }
        __syncthreads();
#pragma unroll
        for (int k = 0; k < KT; k++) {
            float a[8], b[8];
            *(float4*)&a[0] = *(float4*)&hs[k][ty * 8];
            *(float4*)&a[4] = *(float4*)&hs[k][ty * 8 + 4];
            *(float4*)&b[0] = *(float4*)&ws[k][tx * 8];
            *(float4*)&b[4] = *(float4*)&ws[k][tx * 8 + 4];
#pragma unroll
            for (int i = 0; i < 8; i++)
#pragma unroll
                for (int j = 0; j < 8; j++) acc[i][j] = fmaf(a[i], b[j], acc[i][j]);
        }
        __syncthreads();
    }
#pragma unroll
    for (int i = 0; i < 8; i++) {
        int r = r0 + ty * 8 + i;
        if (r < n) {
            *(float4*)(out + (size_t)r * 128 + tx * 8) =
                make_float4(acc[i][0], acc[i][1], acc[i][2], acc[i][3]);
            *(float4*)(out + (size_t)r * 128 + tx * 8 + 4) =
                make_float4(acc[i][4], acc[i][5], acc[i][6], acc[i][7]);
        }
    }
}

// GEMV with fused input norm: out[n] = relu(h[n,128]*S+T) @ W[128]
__global__ void gemv_norm_kernel(const float* __restrict__ h, const float* __restrict__ W,
                                 const float* __restrict__ ss, float* __restrict__ out, int n) {
    int gid = blockIdx.x * blockDim.x + threadIdx.x;
    int wid = gid >> 6, lane = gid & 63;
    int nw = (gridDim.x * blockDim.x) >> 6;
    float w0 = W[lane], w1 = W[64 + lane];
    float s0 = ss[lane], s1 = ss[64 + lane];
    float t0 = ss[128 + lane], t1 = ss[192 + lane];
    for (int r = wid; r < n; r += nw) {
        const float* hr = h + (size_t)r * 128;
        float a = fmaxf(fmaf(hr[lane], s0, t0), 0.f);
        float b = fmaxf(fmaf(hr[64 + lane], s1, t1), 0.f);
        float v = fmaf(a, w0, b * w1);
#pragma unroll
        for (int off = 32; off > 0; off >>= 1) v += __shfl_down(v, off, 64);
        if (lane == 0) out[r] = v;
    }
}

// ================= CSR gather aggregate (fused self-loop, no atomics) =================
// agg[d,c] = tmp[d,c]*dinv[d]^2 + sum_j tmp[esrc_j,c]*dinv[esrc_j]*dinv[d]
__global__ __launch_bounds__(256) void agg128_csr(const float* __restrict__ tmp,
                                                  const int* __restrict__ rowptr,
                                                  const int* __restrict__ esrc,
                                                  const float* __restrict__ dinv,
                                                  float* __restrict__ agg, int n) {
    int node = blockIdx.x * 2 + (threadIdx.x >> 7);
    int c = threadIdx.x & 127;
    if (node >= n) return;
    float di = dinv[node];
    float acc = tmp[(size_t)node * 128 + c] * di * di;
    int beg = rowptr[node], end = rowptr[node + 1];
    for (int j = beg; j < end; j++) {
        int s = esrc[j];
        acc = fmaf(tmp[(size_t)s * 128 + c], dinv[s] * di, acc);
    }
    agg[(size_t)node * 128 + c] = acc;
}

__global__ void agg1_csr(const float* __restrict__ tmp, const int* __restrict__ rowptr,
                         const int* __restrict__ esrc, const float* __restrict__ dinv,
                         float* __restrict__ out, int n) {
    int i = blockIdx.x * blockDim.x + threadIdx.x;
    if (i >= n) return;
    float di = dinv[i];
    float acc = tmp[i] * di * di;
    int beg = rowptr[i], end = rowptr[i + 1];
    for (int j = beg; j < end; j++) {
        int s = esrc[j];
        acc = fmaf(tmp[s], dinv[s] * di, acc);
    }
    out[i] = acc;
}

// ================= stats =================
__global__ __launch_bounds__(256) void stats128_kernel(const float* __restrict__ a,
                                                       float* __restrict__ sums, int n) {
    __shared__ float ls[256], lq[256];
    int t = threadIdx.x;
    int c = t & 127;
    int half = t >> 7;
    float s = 0.f, q = 0.f;
    for (int r = blockIdx.x * 2 + half; r < n; r += gridDim.x * 2) {
        float v = a[(size_t)r * 128 + c];
        s += v;
        q += v * v;
    }
    ls[t] = s;
    lq[t] = q;
    __syncthreads();
    if (half == 0) {
        atomicAdd(&sums[c], ls[c] + ls[c + 128]);
        atomicAdd(&sums[128 + c], lq[c] + lq[c + 128]);
    }
}

__global__ void stats1_kernel(const float* __restrict__ a, float* __restrict__ sums, int n) {
    int gid = blockIdx.x * blockDim.x + threadIdx.x;
    float s = 0.f, q = 0.f;
    for (int i = gid; i < n; i += gridDim.x * blockDim.x) {
        float v = a[i];
        s += v;
        q += v * v;
    }
#pragma unroll
    for (int off = 32; off > 0; off >>= 1) {
        s += __shfl_down(s, off, 64);
        q += __shfl_down(q, off, 64);
    }
    if ((threadIdx.x & 63) == 0) {
        atomicAdd(&sums[0], s);
        atomicAdd(&sums[1], q);
    }
}

// ================= finalize: fused BN->IN->LN =================
template <int C>
__global__ void finalize_kernel(const float* __restrict__ sums, const float* __restrict__ g,
                                const float* __restrict__ lw, const float* __restrict__ lb,
                                float* __restrict__ ss, int n) {
    __shared__ float vt2[C];
    int c = threadIdx.x;
    float m = sums[c] / n;
    float v = sums[C + c] / n - m * m;
    v = v < 0.f ? 0.f : v;
    float gc = g[c];
    float bs = rsqrtf(v + EPS) * gc;
    float vz = v * bs * bs;
    float t = bs * rsqrtf(vz + EPS);
    vt2[c] = v * t * t;
    __syncthreads();
    if (c == 0) {
        float gv = 0.f;
        for (int i = 0; i < C; i++) gv += vt2[i];
        vt2[0] = gv / C;
    }
    __syncthreads();
    float GV = vt2[0];
    float S = t * rsqrtf(GV + EPS) * lw[c];
    ss[c] = S;
    ss[C + c] = lb[c] - m * S;
}

template <int C, bool RELU>
__global__ void apply_kernel(const float* __restrict__ ss, const float* a, float* out, int n) {
    int i = blockIdx.x * blockDim.x + threadIdx.x;
    if (i < n * C) {
        int c = (C == 1) ? 0 : (i & (C - 1));
        float y = fmaf(a[i], ss[c], ss[C + c]);
        if (RELU) y = y > 0.f ? y : 0.f;
        out[i] = y;
    }
}

extern "C" void kernel_launch(void* const* d_in, const int* in_sizes, int n_in,
                              void* d_out, int out_size, void* d_ws, size_t ws_size,
                              hipStream_t stream) {
    const float* x = (const float*)d_in[0];
    const int* ei = (const int*)d_in[1];
    int n = in_sizes[0] / 32;
    int E = in_sizes[1] / 2;
    const int* src = ei;
    const int* dstp = ei + E;
    const float* W1 = (const float*)d_in[2];
    const float* g1 = (const float*)d_in[4];
    const float* lw1 = (const float*)d_in[6];
    const float* lb1 = (const float*)d_in[7];
    const float* W2 = (const float*)d_in[8];
    const float* g2 = (const float*)d_in[10];
    const float* lw2 = (const float*)d_in[12];
    const float* lb2 = (const float*)d_in[13];
    const float* W3 = (const float*)d_in[14];
    const float* g3 = (const float*)d_in[16];
    const float* lw3 = (const float*)d_in[18];
    const float* lb3 = (const float*)d_in[19];
    float* out = (float*)d_out;

    // workspace layout
    char* p = (char*)d_ws;
    int* counts = (int*)p;          p += (size_t)n * 4;        // also reused as fill cursor
    int* rowptr = (int*)p;          p += (size_t)(n + 1) * 4;
    int* aux = (int*)p;             p += 128 * 4;
    int* esrc = (int*)p;            p += (size_t)E * 4;
    float* dinv = (float*)p;        p += (size_t)n * 4;
    float* buf0 = (float*)p;        p += (size_t)n * 128 * 4;
    float* buf1 = (float*)p;        p += (size_t)n * 128 * 4;
    float* sums1 = (float*)p;       p += 256 * 4;
    float* sums2 = (float*)p;       p += 256 * 4;
    float* sums3 = (float*)p;       p += 4 * 4;
    float* ss1 = (float*)p;         p += 256 * 4;
    float* ss2 = (float*)p;         p += 256 * 4;
    float* ss3 = (float*)p;         p += 4 * 4;
    float* buf2 = buf0;             // layer-3 scalars reuse buf0
    float* buf3 = buf0 + n;

    int B = (n + 1023) / 1024;

    // ---- CSR build ----
    hipMemsetAsync(counts, 0, (size_t)n * 4, stream);
    hipMemsetAsync(sums1, 0, 516 * 4, stream);  // sums1+sums2+sums3 contiguous
    hist_kernel<<<(E + 255) / 256, 256, 0, stream>>>(dstp, E, counts);
    dinv_kernel<<<(n + 255) / 256, 256, 0, stream>>>(counts, dinv, n);
    scan_part<<<B, 1024, 0, stream>>>(counts, rowptr, aux, n);
    scan_aux<<<1, 128, 0, stream>>>(aux, B);
    scan_add<<<(n + 255) / 256, 256, 0, stream>>>(rowptr, aux, n, E);
    hipMemsetAsync(counts, 0, (size_t)n * 4, stream);  // reuse as cursor
    fill_kernel<<<(E + 255) / 256, 256, 0, stream>>>(src, dstp, E, rowptr, counts, esrc);

    int gblk = (n + 127) / 128;
    int ablk = (n + 1) / 2;

    // ---- layer 1: 32 -> 128 ----
    gemm_tiled<32, false><<<gblk, 256, 0, stream>>>(x, W1, nullptr, buf0, n);
    agg128_csr<<<ablk, 256, 0, stream>>>(buf0, rowptr, esrc, dinv, buf1, n);
    stats128_kernel<<<1024, 256, 0, stream>>>(buf1, sums1, n);
    finalize_kernel<128><<<1, 128, 0, stream>>>(sums1, g1, lw1, lb1, ss1, n);

    // ---- layer 2: 128 -> 128 (input norm fused into gemm load) ----
    gemm_tiled<128, true><<<gblk, 256, 0, stream>>>(buf1, W2, ss1, buf0, n);
    agg128_csr<<<ablk, 256, 0, stream>>>(buf0, rowptr, esrc, dinv, buf1, n);
    stats128_kernel<<<1024, 256, 0, stream>>>(buf1, sums2, n);
    finalize_kernel<128><<<1, 128, 0, stream>>>(sums2, g2, lw2, lb2, ss2, n);

    // ---- layer 3: 128 -> 1 (input norm fused into gemv) ----
    gemv_norm_kernel<<<1024, 256, 0, stream>>>(buf1, W3, ss2, buf2, n);
    agg1_csr<<<(n + 255) / 256, 256, 0, stream>>>(buf2, rowptr, esrc, dinv, buf3, n);
    stats1_kernel<<<256, 256, 0, stream>>>(buf3, sums3, n);
    finalize_kernel<1><<<1, 1, 0, stream>>>(sums3, g3, lw3, lb3, ss3, n);
    apply_kernel<1, false><<<(n + 255) / 256, 256, 0, stream>>>(ss3, buf3, out, n);
}

// Round 4
// 462.376 us; speedup vs baseline: 2.4270x; 1.2557x over previous
//
#include <hip/hip_runtime.h>
#include <cstddef>

#define EPS 1e-5f

// ================= CSR build (by dst) =================
__global__ void hist_kernel(const int* __restrict__ dst, int E, int* __restrict__ counts) {
    int i = blockIdx.x * blockDim.x + threadIdx.x;
    if (i < E) atomicAdd(&counts[dst[i]], 1);
}

__global__ void dinv_kernel(const int* __restrict__ counts, float* __restrict__ dinv, int n) {
    int i = blockIdx.x * blockDim.x + threadIdx.x;
    if (i < n) dinv[i] = rsqrtf((float)counts[i] + 1.0f);  // +1 = self loop
}

__global__ __launch_bounds__(1024) void scan_part(const int* __restrict__ counts,
                                                  int* __restrict__ rowptr,
                                                  int* __restrict__ aux, int n) {
    __shared__ int sh[1024];
    int t = threadIdx.x;
    int g = blockIdx.x * 1024 + t;
    int v = (g < n) ? counts[g] : 0;
    sh[t] = v;
    __syncthreads();
    for (int off = 1; off < 1024; off <<= 1) {
        int add = (t >= off) ? sh[t - off] : 0;
        __syncthreads();
        sh[t] += add;
        __syncthreads();
    }
    if (g < n) rowptr[g] = sh[t] - v;  // exclusive
    if (t == 1023) aux[blockIdx.x] = sh[t];
}

__global__ __launch_bounds__(128) void scan_aux(int* __restrict__ aux, int B) {
    __shared__ int sh[128];
    int t = threadIdx.x;
    int v = (t < B) ? aux[t] : 0;
    sh[t] = v;
    __syncthreads();
    for (int off = 1; off < 128; off <<= 1) {
        int add = (t >= off) ? sh[t - off] : 0;
        __syncthreads();
        sh[t] += add;
        __syncthreads();
    }
    if (t < B) aux[t] = sh[t] - v;
}

__global__ void scan_add(int* __restrict__ rowptr, const int* __restrict__ aux, int n, int E) {
    int g = blockIdx.x * blockDim.x + threadIdx.x;
    if (g < n) rowptr[g] += aux[g >> 10];
    if (g == 0) rowptr[n] = E;
}

// cursor pre-seeded with rowptr values; writes src index + edge weight per slot
__global__ void fill_kernel(const int* __restrict__ src, const int* __restrict__ dst, int E,
                            int* __restrict__ cur, const float* __restrict__ dinv,
                            int* __restrict__ esrc, float* __restrict__ ewt) {
    int e = blockIdx.x * blockDim.x + threadIdx.x;
    if (e < E) {
        int d = dst[e];
        int s = src[e];
        int p = atomicAdd(&cur[d], 1);
        esrc[p] = s;
        ewt[p] = dinv[s] * dinv[d];
    }
}

// ================= tiled GEMM: out[n,128] = norm(h[n,K]) @ W[K,128] =================
template <int K, bool NORM>
__global__ __launch_bounds__(256) void gemm_tiled(const float* __restrict__ h,
                                                  const float* __restrict__ W,
                                                  const float* __restrict__ ss,
                                                  float* __restrict__ out, int n) {
    constexpr int KT = 16;
    __shared__ float hs[KT][128];
    __shared__ float ws[KT][128];
    int tid = threadIdx.x;
    int tx = tid & 15;
    int ty = tid >> 4;
    int r0 = blockIdx.x * 128;

    float acc[8][8];
#pragma unroll
    for (int i = 0; i < 8; i++)
#pragma unroll
        for (int j = 0; j < 8; j++) acc[i][j] = 0.0f;

    int srow = tid >> 1;
    int skq = (tid & 1) * 8;
    int gr = r0 + srow;

    for (int k0 = 0; k0 < K; k0 += KT) {
#pragma unroll
        for (int half = 0; half < 2; half++) {
            int kk = skq + half * 4;
            float4 v = make_float4(0.f, 0.f, 0.f, 0.f);
            if (gr < n) v = *(const float4*)(h + (size_t)gr * K + k0 + kk);
            if (NORM) {
                float4 s = *(const float4*)(ss + k0 + kk);
                float4 t = *(const float4*)(ss + K + k0 + kk);
                v.x = fmaxf(fmaf(v.x, s.x, t.x), 0.f);
                v.y = fmaxf(fmaf(v.y, s.y, t.y), 0.f);
                v.z = fmaxf(fmaf(v.z, s.z, t.z), 0.f);
                v.w = fmaxf(fmaf(v.w, s.w, t.w), 0.f);
            }
            hs[kk + 0][srow] = v.x;
            hs[kk + 1][srow] = v.y;
            hs[kk + 2][srow] = v.z;
            hs[kk + 3][srow] = v.w;
        }
#pragma unroll
        for (int j = 0; j < 2; j++) {
            int f = tid + j * 256;
            int kk = f >> 5;
            int cc = (f & 31) * 4;
            *(float4*)&ws[kk][cc] = *(const float4*)(W + (size_t)(k0 + kk) * 128 + cc);
        }
        __syncthreads();
#pragma unroll
        for (int k = 0; k < KT; k++) {
            float a[8], b[8];
            *(float4*)&a[0] = *(float4*)&hs[k][ty * 8];
            *(float4*)&a[4] = *(float4*)&hs[k][ty * 8 + 4];
            *(float4*)&b[0] = *(float4*)&ws[k][tx * 8];
            *(float4*)&b[4] = *(float4*)&ws[k][tx * 8 + 4];
#pragma unroll
            for (int i = 0; i < 8; i++)
#pragma unroll
                for (int j = 0; j < 8; j++) acc[i][j] = fmaf(a[i], b[j], acc[i][j]);
        }
        __syncthreads();
    }
#pragma unroll
    for (int i = 0; i < 8; i++) {
        int r = r0 + ty * 8 + i;
        if (r < n) {
            *(float4*)(out + (size_t)r * 128 + tx * 8) =
                make_float4(acc[i][0], acc[i][1], acc[i][2], acc[i][3]);
            *(float4*)(out + (size_t)r * 128 + tx * 8 + 4) =
                make_float4(acc[i][4], acc[i][5], acc[i][6], acc[i][7]);
        }
    }
}

// GEMV with fused input norm: out[n] = relu(h[n,128]*S+T) @ W[128]
__global__ void gemv_norm_kernel(const float* __restrict__ h, const float* __restrict__ W,
                                 const float* __restrict__ ss, float* __restrict__ out, int n) {
    int gid = blockIdx.x * blockDim.x + threadIdx.x;
    int wid = gid >> 6, lane = gid & 63;
    int nw = (gridDim.x * blockDim.x) >> 6;
    float w0 = W[lane], w1 = W[64 + lane];
    float s0 = ss[lane], s1 = ss[64 + lane];
    float t0 = ss[128 + lane], t1 = ss[192 + lane];
    for (int r = wid; r < n; r += nw) {
        const float* hr = h + (size_t)r * 128;
        float a = fmaxf(fmaf(hr[lane], s0, t0), 0.f);
        float b = fmaxf(fmaf(hr[64 + lane], s1, t1), 0.f);
        float v = fmaf(a, w0, b * w1);
#pragma unroll
        for (int off = 32; off > 0; off >>= 1) v += __shfl_down(v, off, 64);
        if (lane == 0) out[r] = v;
    }
}

// ================= CSR gather aggregate (fused self-loop, no atomics) =================
// 128-channel: 32 lanes/node, float4 per lane, edge loop unrolled x4 for MLP.
__global__ __launch_bounds__(256) void agg128_csr(const float* __restrict__ tmp,
                                                  const int* __restrict__ rowptr,
                                                  const int* __restrict__ esrc,
                                                  const float* __restrict__ ewt,
                                                  const float* __restrict__ dinv,
                                                  float* __restrict__ agg, int n) {
    int node = (blockIdx.x << 3) + (threadIdx.x >> 5);
    if (node >= n) return;
    int c4 = threadIdx.x & 31;  // float4 channel index
    float di = dinv[node];
    float d2 = di * di;
    float4 acc = ((const float4*)(tmp + ((size_t)node << 7)))[c4];
    acc.x *= d2; acc.y *= d2; acc.z *= d2; acc.w *= d2;
    int j = rowptr[node], end = rowptr[node + 1];
    for (; j + 4 <= end; j += 4) {
        int s0 = esrc[j], s1 = esrc[j + 1], s2 = esrc[j + 2], s3 = esrc[j + 3];
        float w0 = ewt[j], w1 = ewt[j + 1], w2 = ewt[j + 2], w3 = ewt[j + 3];
        float4 v0 = ((const float4*)(tmp + ((size_t)s0 << 7)))[c4];
        float4 v1 = ((const float4*)(tmp + ((size_t)s1 << 7)))[c4];
        float4 v2 = ((const float4*)(tmp + ((size_t)s2 << 7)))[c4];
        float4 v3 = ((const float4*)(tmp + ((size_t)s3 << 7)))[c4];
        acc.x = fmaf(v0.x, w0, acc.x); acc.y = fmaf(v0.y, w0, acc.y);
        acc.z = fmaf(v0.z, w0, acc.z); acc.w = fmaf(v0.w, w0, acc.w);
        acc.x = fmaf(v1.x, w1, acc.x); acc.y = fmaf(v1.y, w1, acc.y);
        acc.z = fmaf(v1.z, w1, acc.z); acc.w = fmaf(v1.w, w1, acc.w);
        acc.x = fmaf(v2.x, w2, acc.x); acc.y = fmaf(v2.y, w2, acc.y);
        acc.z = fmaf(v2.z, w2, acc.z); acc.w = fmaf(v2.w, w2, acc.w);
        acc.x = fmaf(v3.x, w3, acc.x); acc.y = fmaf(v3.y, w3, acc.y);
        acc.z = fmaf(v3.z, w3, acc.z); acc.w = fmaf(v3.w, w3, acc.w);
    }
    if (j + 2 <= end) {
        int s0 = esrc[j], s1 = esrc[j + 1];
        float w0 = ewt[j], w1 = ewt[j + 1];
        float4 v0 = ((const float4*)(tmp + ((size_t)s0 << 7)))[c4];
        float4 v1 = ((const float4*)(tmp + ((size_t)s1 << 7)))[c4];
        acc.x = fmaf(v0.x, w0, acc.x); acc.y = fmaf(v0.y, w0, acc.y);
        acc.z = fmaf(v0.z, w0, acc.z); acc.w = fmaf(v0.w, w0, acc.w);
        acc.x = fmaf(v1.x, w1, acc.x); acc.y = fmaf(v1.y, w1, acc.y);
        acc.z = fmaf(v1.z, w1, acc.z); acc.w = fmaf(v1.w, w1, acc.w);
        j += 2;
    }
    if (j < end) {
        int s0 = esrc[j];
        float w0 = ewt[j];
        float4 v0 = ((const float4*)(tmp + ((size_t)s0 << 7)))[c4];
        acc.x = fmaf(v0.x, w0, acc.x); acc.y = fmaf(v0.y, w0, acc.y);
        acc.z = fmaf(v0.z, w0, acc.z); acc.w = fmaf(v0.w, w0, acc.w);
    }
    ((float4*)(agg + ((size_t)node << 7)))[c4] = acc;
}

// 32-channel (layer-1 input space): 32 lanes/node, scalar channel per lane.
__global__ __launch_bounds__(256) void agg32_csr(const float* __restrict__ x,
                                                 const int* __restrict__ rowptr,
                                                 const int* __restrict__ esrc,
                                                 const float* __restrict__ ewt,
                                                 const float* __restrict__ dinv,
                                                 float* __restrict__ agg, int n) {
    int node = (blockIdx.x << 3) + (threadIdx.x >> 5);
    if (node >= n) return;
    int c = threadIdx.x & 31;
    float di = dinv[node];
    float acc = x[((size_t)node << 5) + c] * di * di;
    int j = rowptr[node], end = rowptr[node + 1];
    for (; j + 4 <= end; j += 4) {
        int s0 = esrc[j], s1 = esrc[j + 1], s2 = esrc[j + 2], s3 = esrc[j + 3];
        float w0 = ewt[j], w1 = ewt[j + 1], w2 = ewt[j + 2], w3 = ewt[j + 3];
        float v0 = x[((size_t)s0 << 5) + c];
        float v1 = x[((size_t)s1 << 5) + c];
        float v2 = x[((size_t)s2 << 5) + c];
        float v3 = x[((size_t)s3 << 5) + c];
        acc = fmaf(v0, w0, acc);
        acc = fmaf(v1, w1, acc);
        acc = fmaf(v2, w2, acc);
        acc = fmaf(v3, w3, acc);
    }
    for (; j < end; j++) {
        acc = fmaf(x[((size_t)esrc[j] << 5) + c], ewt[j], acc);
    }
    agg[((size_t)node << 5) + c] = acc;
}

__global__ void agg1_csr(const float* __restrict__ tmp, const int* __restrict__ rowptr,
                         const int* __restrict__ esrc, const float* __restrict__ ewt,
                         const float* __restrict__ dinv, float* __restrict__ out, int n) {
    int i = blockIdx.x * blockDim.x + threadIdx.x;
    if (i >= n) return;
    float di = dinv[i];
    float acc = tmp[i] * di * di;
    int beg = rowptr[i], end = rowptr[i + 1];
    for (int j = beg; j < end; j++) {
        acc = fmaf(tmp[esrc[j]], ewt[j], acc);
    }
    out[i] = acc;
}

// ================= stats =================
__global__ __launch_bounds__(256) void stats128_kernel(const float* __restrict__ a,
                                                       float* __restrict__ sums, int n) {
    __shared__ float ls[256], lq[256];
    int t = threadIdx.x;
    int c = t & 127;
    int half = t >> 7;
    float s = 0.f, q = 0.f;
    for (int r = blockIdx.x * 2 + half; r < n; r += gridDim.x * 2) {
        float v = a[(size_t)r * 128 + c];
        s += v;
        q += v * v;
    }
    ls[t] = s;
    lq[t] = q;
    __syncthreads();
    if (half == 0) {
        atomicAdd(&sums[c], ls[c] + ls[c + 128]);
        atomicAdd(&sums[128 + c], lq[c] + lq[c + 128]);
    }
}

__global__ void stats1_kernel(const float* __restrict__ a, float* __restrict__ sums, int n) {
    int gid = blockIdx.x * blockDim.x + threadIdx.x;
    float s = 0.f, q = 0.f;
    for (int i = gid; i < n; i += gridDim.x * blockDim.x) {
        float v = a[i];
        s += v;
        q += v * v;
    }
#pragma unroll
    for (int off = 32; off > 0; off >>= 1) {
        s += __shfl_down(s, off, 64);
        q += __shfl_down(q, off, 64);
    }
    if ((threadIdx.x & 63) == 0) {
        atomicAdd(&sums[0], s);
        atomicAdd(&sums[1], q);
    }
}

// ================= finalize: fused BN->IN->LN =================
template <int C>
__global__ void finalize_kernel(const float* __restrict__ sums, const float* __restrict__ g,
                                const float* __restrict__ lw, const float* __restrict__ lb,
                                float* __restrict__ ss, int n) {
    __shared__ float vt2[C];
    int c = threadIdx.x;
    float m = sums[c] / n;
    float v = sums[C + c] / n - m * m;
    v = v < 0.f ? 0.f : v;
    float gc = g[c];
    float bs = rsqrtf(v + EPS) * gc;
    float vz = v * bs * bs;
    float t = bs * rsqrtf(vz + EPS);
    vt2[c] = v * t * t;
    __syncthreads();
    if (c == 0) {
        float gv = 0.f;
        for (int i = 0; i < C; i++) gv += vt2[i];
        vt2[0] = gv / C;
    }
    __syncthreads();
    float GV = vt2[0];
    float S = t * rsqrtf(GV + EPS) * lw[c];
    ss[c] = S;
    ss[C + c] = lb[c] - m * S;
}

template <int C, bool RELU>
__global__ void apply_kernel(const float* __restrict__ ss, const float* a, float* out, int n) {
    int i = blockIdx.x * blockDim.x + threadIdx.x;
    if (i < n * C) {
        int c = (C == 1) ? 0 : (i & (C - 1));
        float y = fmaf(a[i], ss[c], ss[C + c]);
        if (RELU) y = y > 0.f ? y : 0.f;
        out[i] = y;
    }
}

extern "C" void kernel_launch(void* const* d_in, const int* in_sizes, int n_in,
                              void* d_out, int out_size, void* d_ws, size_t ws_size,
                              hipStream_t stream) {
    const float* x = (const float*)d_in[0];
    const int* ei = (const int*)d_in[1];
    int n = in_sizes[0] / 32;
    int E = in_sizes[1] / 2;
    const int* src = ei;
    const int* dstp = ei + E;
    const float* W1 = (const float*)d_in[2];
    const float* g1 = (const float*)d_in[4];
    const float* lw1 = (const float*)d_in[6];
    const float* lb1 = (const float*)d_in[7];
    const float* W2 = (const float*)d_in[8];
    const float* g2 = (const float*)d_in[10];
    const float* lw2 = (const float*)d_in[12];
    const float* lb2 = (const float*)d_in[13];
    const float* W3 = (const float*)d_in[14];
    const float* g3 = (const float*)d_in[16];
    const float* lw3 = (const float*)d_in[18];
    const float* lb3 = (const float*)d_in[19];
    float* out = (float*)d_out;

    // workspace layout
    char* p = (char*)d_ws;
    int* counts = (int*)p;          p += (size_t)n * 4;   // hist; then fill cursor
    int* rowptr = (int*)p;          p += (size_t)(n + 1) * 4;
    int* aux = (int*)p;             p += 128 * 4;
    int* esrc = (int*)p;            p += (size_t)E * 4;
    float* ewt = (float*)p;         p += (size_t)E * 4;
    float* dinv = (float*)p;        p += (size_t)n * 4;
    float* buf0 = (float*)p;        p += (size_t)n * 128 * 4;
    float* buf1 = (float*)p;        p += (size_t)n * 128 * 4;
    float* sums1 = (float*)p;       p += 256 * 4;
    float* sums2 = (float*)p;       p += 256 * 4;
    float* sums3 = (float*)p;       p += 4 * 4;
    float* ss1 = (float*)p;         p += 256 * 4;
    float* ss2 = (float*)p;         p += 256 * 4;
    float* ss3 = (float*)p;         p += 4 * 4;
    float* xa = buf0;               // aggregated x (n x 32), reuses buf0
    float* buf2 = buf0;             // layer-3 scalars reuse buf0
    float* buf3 = buf0 + n;

    int B = (n + 1023) / 1024;

    // ---- CSR build ----
    hipMemsetAsync(counts, 0, (size_t)n * 4, stream);
    hipMemsetAsync(sums1, 0, 516 * 4, stream);  // sums1+sums2+sums3 contiguous
    hist_kernel<<<(E + 255) / 256, 256, 0, stream>>>(dstp, E, counts);
    dinv_kernel<<<(n + 255) / 256, 256, 0, stream>>>(counts, dinv, n);
    scan_part<<<B, 1024, 0, stream>>>(counts, rowptr, aux, n);
    scan_aux<<<1, 128, 0, stream>>>(aux, B);
    scan_add<<<(n + 255) / 256, 256, 0, stream>>>(rowptr, aux, n, E);
    hipMemcpyAsync(counts, rowptr, (size_t)n * 4, hipMemcpyDeviceToDevice, stream);
    fill_kernel<<<(E + 255) / 256, 256, 0, stream>>>(src, dstp, E, counts, dinv, esrc, ewt);

    int gblk = (n + 127) / 128;
    int nblk8 = (n + 7) / 8;

    // ---- layer 1: agg in 32-dim input space, then GEMM 32->128 ----
    agg32_csr<<<nblk8, 256, 0, stream>>>(x, rowptr, esrc, ewt, dinv, xa, n);
    gemm_tiled<32, false><<<gblk, 256, 0, stream>>>(xa, W1, nullptr, buf1, n);
    stats128_kernel<<<1024, 256, 0, stream>>>(buf1, sums1, n);
    finalize_kernel<128><<<1, 128, 0, stream>>>(sums1, g1, lw1, lb1, ss1, n);

    // ---- layer 2: 128 -> 128 (input norm fused into gemm load) ----
    gemm_tiled<128, true><<<gblk, 256, 0, stream>>>(buf1, W2, ss1, buf0, n);
    agg128_csr<<<nblk8, 256, 0, stream>>>(buf0, rowptr, esrc, ewt, dinv, buf1, n);
    stats128_kernel<<<1024, 256, 0, stream>>>(buf1, sums2, n);
    finalize_kernel<128><<<1, 128, 0, stream>>>(sums2, g2, lw2, lb2, ss2, n);

    // ---- layer 3: 128 -> 1 (input norm fused into gemv) ----
    gemv_norm_kernel<<<1024, 256, 0, stream>>>(buf1, W3, ss2, buf2, n);
    agg1_csr<<<(n + 255) / 256, 256, 0, stream>>>(buf2, rowptr, esrc, ewt, dinv, buf3, n);
    stats1_kernel<<<256, 256, 0, stream>>>(buf3, sums3, n);
    finalize_kernel<1><<<1, 1, 0, stream>>>(sums3, g3, lw3, lb3, ss3, n);
    apply_kernel<1, false><<<(n + 255) / 256, 256, 0, stream>>>(ss3, buf3, out, n);
}

// Round 5
// 432.848 us; speedup vs baseline: 2.5926x; 1.0682x over previous
//
#include <hip/hip_runtime.h>
#include <cstddef>

#define EPS 1e-5f

typedef __attribute__((ext_vector_type(8))) short bf16x8;
typedef __attribute__((ext_vector_type(4))) float f32x4;

__device__ inline short f2bf(float f) {
    union { float f; unsigned u; } v;
    v.f = f;
    unsigned r = v.u + 0x7fff + ((v.u >> 16) & 1);  // round-to-nearest-even
    return (short)(r >> 16);
}

// ================= CSR build (by dst) =================
__global__ void hist_kernel(const int* __restrict__ dst, int E, int* __restrict__ counts) {
    int i = blockIdx.x * blockDim.x + threadIdx.x;
    if (i < E) atomicAdd(&counts[dst[i]], 1);
}

__global__ void dinv_kernel(const int* __restrict__ counts, float* __restrict__ dinv, int n) {
    int i = blockIdx.x * blockDim.x + threadIdx.x;
    if (i < n) dinv[i] = rsqrtf((float)counts[i] + 1.0f);  // +1 = self loop
}

__global__ __launch_bounds__(1024) void scan_part(const int* __restrict__ counts,
                                                  int* __restrict__ rowptr,
                                                  int* __restrict__ aux, int n) {
    __shared__ int sh[1024];
    int t = threadIdx.x;
    int g = blockIdx.x * 1024 + t;
    int v = (g < n) ? counts[g] : 0;
    sh[t] = v;
    __syncthreads();
    for (int off = 1; off < 1024; off <<= 1) {
        int add = (t >= off) ? sh[t - off] : 0;
        __syncthreads();
        sh[t] += add;
        __syncthreads();
    }
    if (g < n) rowptr[g] = sh[t] - v;  // exclusive
    if (t == 1023) aux[blockIdx.x] = sh[t];
}

__global__ __launch_bounds__(128) void scan_aux(int* __restrict__ aux, int B) {
    __shared__ int sh[128];
    int t = threadIdx.x;
    int v = (t < B) ? aux[t] : 0;
    sh[t] = v;
    __syncthreads();
    for (int off = 1; off < 128; off <<= 1) {
        int add = (t >= off) ? sh[t - off] : 0;
        __syncthreads();
        sh[t] += add;
        __syncthreads();
    }
    if (t < B) aux[t] = sh[t] - v;
}

__global__ void scan_add(int* __restrict__ rowptr, const int* __restrict__ aux, int n, int E) {
    int g = blockIdx.x * blockDim.x + threadIdx.x;
    if (g < n) rowptr[g] += aux[g >> 10];
    if (g == 0) rowptr[n] = E;
}

__global__ void fill_kernel(const int* __restrict__ src, const int* __restrict__ dst, int E,
                            int* __restrict__ cur, const float* __restrict__ dinv,
                            int* __restrict__ esrc, float* __restrict__ ewt) {
    int e = blockIdx.x * blockDim.x + threadIdx.x;
    if (e < E) {
        int d = dst[e];
        int s = src[e];
        int p = atomicAdd(&cur[d], 1);
        esrc[p] = s;
        ewt[p] = dinv[s] * dinv[d];
    }
}

// ================= W transpose + bf16 convert: Wt[c][k] = bf16(W[k][c]) =================
__global__ void wt_bf16_kernel(const float* __restrict__ W, short* __restrict__ Wt,
                               int K, int C) {
    int o = blockIdx.x * blockDim.x + threadIdx.x;
    if (o < K * C) {
        int c = o / K, k = o % K;
        Wt[o] = f2bf(W[(size_t)k * C + c]);
    }
}

// ================= MFMA GEMM: out[n,128] = norm(h[n,K]) @ W[K,128] =================
// One wave per 32-row strip; 2x8 tiles of 16x16; no LDS, no barriers.
// A loaded from global fp32 (converted to bf16 in-register), B from bf16 Wt[c][k].
template <int K, bool NORM>
__global__ __launch_bounds__(256) void gemm_mfma(const float* __restrict__ h,
                                                 const short* __restrict__ Wt,
                                                 const float* __restrict__ ss,
                                                 float* __restrict__ out, int n) {
    int wid = (blockIdx.x * 256 + threadIdx.x) >> 6;
    int lane = threadIdx.x & 63;
    int m = lane & 15;
    int qd = lane >> 4;
    int r0 = wid * 32;
    if (r0 >= n) return;

    f32x4 acc[2][8];
#pragma unroll
    for (int rt = 0; rt < 2; rt++)
#pragma unroll
        for (int ct = 0; ct < 8; ct++) acc[rt][ct] = (f32x4){0.f, 0.f, 0.f, 0.f};

#pragma unroll
    for (int q = 0; q < K / 32; q++) {
        int k0 = q * 32 + qd * 8;
        bf16x8 a[2];
#pragma unroll
        for (int rt = 0; rt < 2; rt++) {
            int r = r0 + rt * 16 + m;
            float av[8];
            if (r < n) {
                float4 x0 = *(const float4*)(h + (size_t)r * K + k0);
                float4 x1 = *(const float4*)(h + (size_t)r * K + k0 + 4);
                av[0] = x0.x; av[1] = x0.y; av[2] = x0.z; av[3] = x0.w;
                av[4] = x1.x; av[5] = x1.y; av[6] = x1.z; av[7] = x1.w;
            } else {
#pragma unroll
                for (int j = 0; j < 8; j++) av[j] = 0.f;
            }
            if (NORM) {
                float4 s0 = *(const float4*)(ss + k0);
                float4 s1 = *(const float4*)(ss + k0 + 4);
                float4 t0 = *(const float4*)(ss + K + k0);
                float4 t1 = *(const float4*)(ss + K + k0 + 4);
                av[0] = fmaxf(fmaf(av[0], s0.x, t0.x), 0.f);
                av[1] = fmaxf(fmaf(av[1], s0.y, t0.y), 0.f);
                av[2] = fmaxf(fmaf(av[2], s0.z, t0.z), 0.f);
                av[3] = fmaxf(fmaf(av[3], s0.w, t0.w), 0.f);
                av[4] = fmaxf(fmaf(av[4], s1.x, t1.x), 0.f);
                av[5] = fmaxf(fmaf(av[5], s1.y, t1.y), 0.f);
                av[6] = fmaxf(fmaf(av[6], s1.z, t1.z), 0.f);
                av[7] = fmaxf(fmaf(av[7], s1.w, t1.w), 0.f);
            }
#pragma unroll
            for (int j = 0; j < 8; j++) a[rt][j] = f2bf(av[j]);
        }
#pragma unroll
        for (int ct = 0; ct < 8; ct++) {
            bf16x8 b = *(const bf16x8*)(Wt + (size_t)(ct * 16 + m) * K + k0);
            acc[0][ct] = __builtin_amdgcn_mfma_f32_16x16x32_bf16(a[0], b, acc[0][ct], 0, 0, 0);
            acc[1][ct] = __builtin_amdgcn_mfma_f32_16x16x32_bf16(a[1], b, acc[1][ct], 0, 0, 0);
        }
    }
#pragma unroll
    for (int rt = 0; rt < 2; rt++)
#pragma unroll
        for (int i = 0; i < 4; i++) {
            int r = r0 + rt * 16 + qd * 4 + i;
            if (r < n) {
#pragma unroll
                for (int ct = 0; ct < 8; ct++)
                    out[(size_t)r * 128 + ct * 16 + m] = acc[rt][ct][i];
            }
        }
}

// GEMV with fused input norm: out[n] = relu(h[n,128]*S+T) @ W[128]
__global__ void gemv_norm_kernel(const float* __restrict__ h, const float* __restrict__ W,
                                 const float* __restrict__ ss, float* __restrict__ out, int n) {
    int gid = blockIdx.x * blockDim.x + threadIdx.x;
    int wid = gid >> 6, lane = gid & 63;
    int nw = (gridDim.x * blockDim.x) >> 6;
    float w0 = W[lane], w1 = W[64 + lane];
    float s0 = ss[lane], s1 = ss[64 + lane];
    float t0 = ss[128 + lane], t1 = ss[192 + lane];
    for (int r = wid; r < n; r += nw) {
        const float* hr = h + (size_t)r * 128;
        float a = fmaxf(fmaf(hr[lane], s0, t0), 0.f);
        float b = fmaxf(fmaf(hr[64 + lane], s1, t1), 0.f);
        float v = fmaf(a, w0, b * w1);
#pragma unroll
        for (int off = 32; off > 0; off >>= 1) v += __shfl_down(v, off, 64);
        if (lane == 0) out[r] = v;
    }
}

// ================= CSR gather aggregate (fused self-loop, no atomics) =================
__global__ __launch_bounds__(256) void agg128_csr(const float* __restrict__ tmp,
                                                  const int* __restrict__ rowptr,
                                                  const int* __restrict__ esrc,
                                                  const float* __restrict__ ewt,
                                                  const float* __restrict__ dinv,
                                                  float* __restrict__ agg, int n) {
    int node = (blockIdx.x << 3) + (threadIdx.x >> 5);
    if (node >= n) return;
    int c4 = threadIdx.x & 31;
    float di = dinv[node];
    float d2 = di * di;
    float4 acc = ((const float4*)(tmp + ((size_t)node << 7)))[c4];
    acc.x *= d2; acc.y *= d2; acc.z *= d2; acc.w *= d2;
    int j = rowptr[node], end = rowptr[node + 1];
    for (; j + 4 <= end; j += 4) {
        int s0 = esrc[j], s1 = esrc[j + 1], s2 = esrc[j + 2], s3 = esrc[j + 3];
        float w0 = ewt[j], w1 = ewt[j + 1], w2 = ewt[j + 2], w3 = ewt[j + 3];
        float4 v0 = ((const float4*)(tmp + ((size_t)s0 << 7)))[c4];
        float4 v1 = ((const float4*)(tmp + ((size_t)s1 << 7)))[c4];
        float4 v2 = ((const float4*)(tmp + ((size_t)s2 << 7)))[c4];
        float4 v3 = ((const float4*)(tmp + ((size_t)s3 << 7)))[c4];
        acc.x = fmaf(v0.x, w0, acc.x); acc.y = fmaf(v0.y, w0, acc.y);
        acc.z = fmaf(v0.z, w0, acc.z); acc.w = fmaf(v0.w, w0, acc.w);
        acc.x = fmaf(v1.x, w1, acc.x); acc.y = fmaf(v1.y, w1, acc.y);
        acc.z = fmaf(v1.z, w1, acc.z); acc.w = fmaf(v1.w, w1, acc.w);
        acc.x = fmaf(v2.x, w2, acc.x); acc.y = fmaf(v2.y, w2, acc.y);
        acc.z = fmaf(v2.z, w2, acc.z); acc.w = fmaf(v2.w, w2, acc.w);
        acc.x = fmaf(v3.x, w3, acc.x); acc.y = fmaf(v3.y, w3, acc.y);
        acc.z = fmaf(v3.z, w3, acc.z); acc.w = fmaf(v3.w, w3, acc.w);
    }
    if (j + 2 <= end) {
        int s0 = esrc[j], s1 = esrc[j + 1];
        float w0 = ewt[j], w1 = ewt[j + 1];
        float4 v0 = ((const float4*)(tmp + ((size_t)s0 << 7)))[c4];
        float4 v1 = ((const float4*)(tmp + ((size_t)s1 << 7)))[c4];
        acc.x = fmaf(v0.x, w0, acc.x); acc.y = fmaf(v0.y, w0, acc.y);
        acc.z = fmaf(v0.z, w0, acc.z); acc.w = fmaf(v0.w, w0, acc.w);
        acc.x = fmaf(v1.x, w1, acc.x); acc.y = fmaf(v1.y, w1, acc.y);
        acc.z = fmaf(v1.z, w1, acc.z); acc.w = fmaf(v1.w, w1, acc.w);
        j += 2;
    }
    if (j < end) {
        int s0 = esrc[j];
        float w0 = ewt[j];
        float4 v0 = ((const float4*)(tmp + ((size_t)s0 << 7)))[c4];
        acc.x = fmaf(v0.x, w0, acc.x); acc.y = fmaf(v0.y, w0, acc.y);
        acc.z = fmaf(v0.z, w0, acc.z); acc.w = fmaf(v0.w, w0, acc.w);
    }
    ((float4*)(agg + ((size_t)node << 7)))[c4] = acc;
}

__global__ __launch_bounds__(256) void agg32_csr(const float* __restrict__ x,
                                                 const int* __restrict__ rowptr,
                                                 const int* __restrict__ esrc,
                                                 const float* __restrict__ ewt,
                                                 const float* __restrict__ dinv,
                                                 float* __restrict__ agg, int n) {
    int node = (blockIdx.x << 3) + (threadIdx.x >> 5);
    if (node >= n) return;
    int c = threadIdx.x & 31;
    float di = dinv[node];
    float acc = x[((size_t)node << 5) + c] * di * di;
    int j = rowptr[node], end = rowptr[node + 1];
    for (; j + 4 <= end; j += 4) {
        int s0 = esrc[j], s1 = esrc[j + 1], s2 = esrc[j + 2], s3 = esrc[j + 3];
        float w0 = ewt[j], w1 = ewt[j + 1], w2 = ewt[j + 2], w3 = ewt[j + 3];
        float v0 = x[((size_t)s0 << 5) + c];
        float v1 = x[((size_t)s1 << 5) + c];
        float v2 = x[((size_t)s2 << 5) + c];
        float v3 = x[((size_t)s3 << 5) + c];
        acc = fmaf(v0, w0, acc);
        acc = fmaf(v1, w1, acc);
        acc = fmaf(v2, w2, acc);
        acc = fmaf(v3, w3, acc);
    }
    for (; j < end; j++) {
        acc = fmaf(x[((size_t)esrc[j] << 5) + c], ewt[j], acc);
    }
    agg[((size_t)node << 5) + c] = acc;
}

__global__ void agg1_csr(const float* __restrict__ tmp, const int* __restrict__ rowptr,
                         const int* __restrict__ esrc, const float* __restrict__ ewt,
                         const float* __restrict__ dinv, float* __restrict__ out, int n) {
    int i = blockIdx.x * blockDim.x + threadIdx.x;
    if (i >= n) return;
    float di = dinv[i];
    float acc = tmp[i] * di * di;
    int beg = rowptr[i], end = rowptr[i + 1];
    for (int j = beg; j < end; j++) {
        acc = fmaf(tmp[esrc[j]], ewt[j], acc);
    }
    out[i] = acc;
}

// ================= stats =================
__global__ __launch_bounds__(256) void stats128_kernel(const float* __restrict__ a,
                                                       float* __restrict__ sums, int n) {
    __shared__ float ls[256], lq[256];
    int t = threadIdx.x;
    int c = t & 127;
    int half = t >> 7;
    float s = 0.f, q = 0.f;
    for (int r = blockIdx.x * 2 + half; r < n; r += gridDim.x * 2) {
        float v = a[(size_t)r * 128 + c];
        s += v;
        q += v * v;
    }
    ls[t] = s;
    lq[t] = q;
    __syncthreads();
    if (half == 0) {
        atomicAdd(&sums[c], ls[c] + ls[c + 128]);
        atomicAdd(&sums[128 + c], lq[c] + lq[c + 128]);
    }
}

__global__ void stats1_kernel(const float* __restrict__ a, float* __restrict__ sums, int n) {
    int gid = blockIdx.x * blockDim.x + threadIdx.x;
    float s = 0.f, q = 0.f;
    for (int i = gid; i < n; i += gridDim.x * blockDim.x) {
        float v = a[i];
        s += v;
        q += v * v;
    }
#pragma unroll
    for (int off = 32; off > 0; off >>= 1) {
        s += __shfl_down(s, off, 64);
        q += __shfl_down(q, off, 64);
    }
    if ((threadIdx.x & 63) == 0) {
        atomicAdd(&sums[0], s);
        atomicAdd(&sums[1], q);
    }
}

// ================= finalize: fused BN->IN->LN =================
template <int C>
__global__ void finalize_kernel(const float* __restrict__ sums, const float* __restrict__ g,
                                const float* __restrict__ lw, const float* __restrict__ lb,
                                float* __restrict__ ss, int n) {
    __shared__ float vt2[C];
    int c = threadIdx.x;
    float m = sums[c] / n;
    float v = sums[C + c] / n - m * m;
    v = v < 0.f ? 0.f : v;
    float gc = g[c];
    float bs = rsqrtf(v + EPS) * gc;
    float vz = v * bs * bs;
    float t = bs * rsqrtf(vz + EPS);
    vt2[c] = v * t * t;
    __syncthreads();
    if (c == 0) {
        float gv = 0.f;
        for (int i = 0; i < C; i++) gv += vt2[i];
        vt2[0] = gv / C;
    }
    __syncthreads();
    float GV = vt2[0];
    float S = t * rsqrtf(GV + EPS) * lw[c];
    ss[c] = S;
    ss[C + c] = lb[c] - m * S;
}

template <int C, bool RELU>
__global__ void apply_kernel(const float* __restrict__ ss, const float* a, float* out, int n) {
    int i = blockIdx.x * blockDim.x + threadIdx.x;
    if (i < n * C) {
        int c = (C == 1) ? 0 : (i & (C - 1));
        float y = fmaf(a[i], ss[c], ss[C + c]);
        if (RELU) y = y > 0.f ? y : 0.f;
        out[i] = y;
    }
}

extern "C" void kernel_launch(void* const* d_in, const int* in_sizes, int n_in,
                              void* d_out, int out_size, void* d_ws, size_t ws_size,
                              hipStream_t stream) {
    const float* x = (const float*)d_in[0];
    const int* ei = (const int*)d_in[1];
    int n = in_sizes[0] / 32;
    int E = in_sizes[1] / 2;
    const int* src = ei;
    const int* dstp = ei + E;
    const float* W1 = (const float*)d_in[2];
    const float* g1 = (const float*)d_in[4];
    const float* lw1 = (const float*)d_in[6];
    const float* lb1 = (const float*)d_in[7];
    const float* W2 = (const float*)d_in[8];
    const float* g2 = (const float*)d_in[10];
    const float* lw2 = (const float*)d_in[12];
    const float* lb2 = (const float*)d_in[13];
    const float* W3 = (const float*)d_in[14];
    const float* g3 = (const float*)d_in[16];
    const float* lw3 = (const float*)d_in[18];
    const float* lb3 = (const float*)d_in[19];
    float* out = (float*)d_out;

    // workspace layout (16B-aligned chunks)
    char* p = (char*)d_ws;
    int* counts = (int*)p;          p += (size_t)n * 4;
    int* rowptr = (int*)p;          p += (size_t)(n + 4) * 4;
    int* aux = (int*)p;             p += 128 * 4;
    int* esrc = (int*)p;            p += (size_t)E * 4;
    float* ewt = (float*)p;         p += (size_t)E * 4;
    float* dinv = (float*)p;        p += (size_t)n * 4;
    short* Wt1 = (short*)p;         p += 128 * 32 * 2;
    short* Wt2 = (short*)p;         p += 128 * 128 * 2;
    float* buf0 = (float*)p;        p += (size_t)n * 128 * 4;
    float* buf1 = (float*)p;        p += (size_t)n * 128 * 4;
    float* sums1 = (float*)p;       p += 256 * 4;
    float* sums2 = (float*)p;       p += 256 * 4;
    float* sums3 = (float*)p;       p += 4 * 4;
    float* ss1 = (float*)p;         p += 256 * 4;
    float* ss2 = (float*)p;         p += 256 * 4;
    float* ss3 = (float*)p;         p += 4 * 4;
    float* xa = buf0;               // aggregated x (n x 32), reuses buf0
    float* buf2 = buf0;             // layer-3 scalars reuse buf0
    float* buf3 = buf0 + n;

    int B = (n + 1023) / 1024;

    // ---- CSR build + weight prep ----
    hipMemsetAsync(counts, 0, (size_t)n * 4, stream);
    hipMemsetAsync(sums1, 0, 516 * 4, stream);
    hist_kernel<<<(E + 255) / 256, 256, 0, stream>>>(dstp, E, counts);
    dinv_kernel<<<(n + 255) / 256, 256, 0, stream>>>(counts, dinv, n);
    scan_part<<<B, 1024, 0, stream>>>(counts, rowptr, aux, n);
    scan_aux<<<1, 128, 0, stream>>>(aux, B);
    scan_add<<<(n + 255) / 256, 256, 0, stream>>>(rowptr, aux, n, E);
    hipMemcpyAsync(counts, rowptr, (size_t)n * 4, hipMemcpyDeviceToDevice, stream);
    fill_kernel<<<(E + 255) / 256, 256, 0, stream>>>(src, dstp, E, counts, dinv, esrc, ewt);
    wt_bf16_kernel<<<(32 * 128 + 255) / 256, 256, 0, stream>>>(W1, Wt1, 32, 128);
    wt_bf16_kernel<<<(128 * 128 + 255) / 256, 256, 0, stream>>>(W2, Wt2, 128, 128);

    int mblk = ((n + 31) / 32 + 3) / 4;  // 4 waves per block, 1 strip of 32 rows each
    int nblk8 = (n + 7) / 8;

    // ---- layer 1: agg in 32-dim input space, then MFMA GEMM 32->128 ----
    agg32_csr<<<nblk8, 256, 0, stream>>>(x, rowptr, esrc, ewt, dinv, xa, n);
    gemm_mfma<32, false><<<mblk, 256, 0, stream>>>(xa, Wt1, nullptr, buf1, n);
    stats128_kernel<<<1024, 256, 0, stream>>>(buf1, sums1, n);
    finalize_kernel<128><<<1, 128, 0, stream>>>(sums1, g1, lw1, lb1, ss1, n);

    // ---- layer 2: MFMA GEMM 128 -> 128 (input norm fused) ----
    gemm_mfma<128, true><<<mblk, 256, 0, stream>>>(buf1, Wt2, ss1, buf0, n);
    agg128_csr<<<nblk8, 256, 0, stream>>>(buf0, rowptr, esrc, ewt, dinv, buf1, n);
    stats128_kernel<<<1024, 256, 0, stream>>>(buf1, sums2, n);
    finalize_kernel<128><<<1, 128, 0, stream>>>(sums2, g2, lw2, lb2, ss2, n);

    // ---- layer 3: 128 -> 1 (input norm fused into gemv) ----
    gemv_norm_kernel<<<1024, 256, 0, stream>>>(buf1, W3, ss2, buf2, n);
    agg1_csr<<<(n + 255) / 256, 256, 0, stream>>>(buf2, rowptr, esrc, ewt, dinv, buf3, n);
    stats1_kernel<<<256, 256, 0, stream>>>(buf3, sums3, n);
    finalize_kernel<1><<<1, 1, 0, stream>>>(sums3, g3, lw3, lb3, ss3, n);
    apply_kernel<1, false><<<(n + 255) / 256, 256, 0, stream>>>(ss3, buf3, out, n);
}

// Round 6
// 382.261 us; speedup vs baseline: 2.9356x; 1.1323x over previous
//
#include <hip/hip_runtime.h>
#include <cstddef>

#define EPS 1e-5f

typedef __attribute__((ext_vector_type(8))) short bf16x8;
typedef __attribute__((ext_vector_type(4))) float f32x4;

__device__ inline short f2bf(float f) {
    union { float f; unsigned u; } v;
    v.f = f;
    unsigned r = v.u + 0x7fff + ((v.u >> 16) & 1);  // RNE
    return (short)(r >> 16);
}
__device__ inline float bf2f(unsigned short s) {
    union { unsigned u; float f; } v;
    v.u = ((unsigned)s) << 16;
    return v.f;
}

// ================= CSR build (by dst) =================
__global__ void hist_kernel(const int* __restrict__ dst, int E, int* __restrict__ counts) {
    int i = blockIdx.x * blockDim.x + threadIdx.x;
    if (i < E) atomicAdd(&counts[dst[i]], 1);
}

__global__ void dinv_kernel(const int* __restrict__ counts, float* __restrict__ dinv, int n) {
    int i = blockIdx.x * blockDim.x + threadIdx.x;
    if (i < n) dinv[i] = rsqrtf((float)counts[i] + 1.0f);
}

__global__ __launch_bounds__(1024) void scan_part(const int* __restrict__ counts,
                                                  int* __restrict__ rowptr,
                                                  int* __restrict__ aux, int n) {
    __shared__ int sh[1024];
    int t = threadIdx.x;
    int g = blockIdx.x * 1024 + t;
    int v = (g < n) ? counts[g] : 0;
    sh[t] = v;
    __syncthreads();
    for (int off = 1; off < 1024; off <<= 1) {
        int add = (t >= off) ? sh[t - off] : 0;
        __syncthreads();
        sh[t] += add;
        __syncthreads();
    }
    if (g < n) rowptr[g] = sh[t] - v;
    if (t == 1023) aux[blockIdx.x] = sh[t];
}

__global__ __launch_bounds__(128) void scan_aux(int* __restrict__ aux, int B) {
    __shared__ int sh[128];
    int t = threadIdx.x;
    int v = (t < B) ? aux[t] : 0;
    sh[t] = v;
    __syncthreads();
    for (int off = 1; off < 128; off <<= 1) {
        int add = (t >= off) ? sh[t - off] : 0;
        __syncthreads();
        sh[t] += add;
        __syncthreads();
    }
    if (t < B) aux[t] = sh[t] - v;
}

__global__ void scan_add(int* __restrict__ rowptr, const int* __restrict__ aux, int n, int E) {
    int g = blockIdx.x * blockDim.x + threadIdx.x;
    if (g < n) rowptr[g] += aux[g >> 10];
    if (g == 0) rowptr[n] = E;
}

__global__ void fill_kernel(const int* __restrict__ src, const int* __restrict__ dst, int E,
                            int* __restrict__ cur, const float* __restrict__ dinv,
                            int* __restrict__ esrc, float* __restrict__ ewt) {
    int e = blockIdx.x * blockDim.x + threadIdx.x;
    if (e < E) {
        int d = dst[e];
        int s = src[e];
        int p = atomicAdd(&cur[d], 1);
        esrc[p] = s;
        ewt[p] = dinv[s] * dinv[d];
    }
}

// ================= weight transpose + bf16: Wt[c][k] =================
__global__ void wt_bf16_kernel(const float* __restrict__ W, unsigned short* __restrict__ Wt,
                               int K, int C) {
    int o = blockIdx.x * blockDim.x + threadIdx.x;
    if (o < K * C) {
        int c = o / K, k = o % K;
        Wt[o] = (unsigned short)f2bf(W[(size_t)k * C + c]);
    }
}

// x -> bf16 (count4 = total/4)
__global__ void cvt_bf16_kernel(const float* __restrict__ in, unsigned short* __restrict__ outp,
                                int count4) {
    int i = blockIdx.x * blockDim.x + threadIdx.x;
    if (i < count4) {
        float4 v = ((const float4*)in)[i];
        ushort4 o;
        o.x = (unsigned short)f2bf(v.x);
        o.y = (unsigned short)f2bf(v.y);
        o.z = (unsigned short)f2bf(v.z);
        o.w = (unsigned short)f2bf(v.w);
        ((ushort4*)outp)[i] = o;
    }
}

// ================= MFMA GEMM: out[n,128] = norm(hb[n,K]) @ W, bf16 in/out =================
// One wave per 32-row strip; 2x8 tiles of 16x16. STATS: fused per-channel sum/sumsq of output.
template <int K, bool NORM, bool STATS>
__global__ __launch_bounds__(256) void gemm_mfma(const unsigned short* __restrict__ hb,
                                                 const unsigned short* __restrict__ Wt,
                                                 const float* __restrict__ ss,
                                                 unsigned short* __restrict__ outb,
                                                 float* __restrict__ sums, int n) {
    int wid = (blockIdx.x * 256 + threadIdx.x) >> 6;
    int wv = (threadIdx.x >> 6);
    int lane = threadIdx.x & 63;
    int m = lane & 15;
    int qd = lane >> 4;
    int r0 = wid * 32;
    if (!STATS && r0 >= n) return;

    f32x4 acc[2][8];
#pragma unroll
    for (int rt = 0; rt < 2; rt++)
#pragma unroll
        for (int ct = 0; ct < 8; ct++) acc[rt][ct] = (f32x4){0.f, 0.f, 0.f, 0.f};

    if (r0 < n) {
#pragma unroll
        for (int q = 0; q < K / 32; q++) {
            int k0 = q * 32 + qd * 8;
            bf16x8 a[2];
#pragma unroll
            for (int rt = 0; rt < 2; rt++) {
                int r = r0 + rt * 16 + m;
                bf16x8 av = (bf16x8){0, 0, 0, 0, 0, 0, 0, 0};
                if (r < n) av = *(const bf16x8*)(hb + (size_t)r * K + k0);
                if (NORM) {
#pragma unroll
                    for (int j = 0; j < 8; j++) {
                        float f = bf2f((unsigned short)av[j]);
                        f = fmaxf(fmaf(f, ss[k0 + j], ss[K + k0 + j]), 0.f);
                        av[j] = f2bf(f);
                    }
                }
                a[rt] = av;
            }
#pragma unroll
            for (int ct = 0; ct < 8; ct++) {
                bf16x8 b = *(const bf16x8*)(Wt + (size_t)(ct * 16 + m) * K + k0);
                acc[0][ct] = __builtin_amdgcn_mfma_f32_16x16x32_bf16(a[0], b, acc[0][ct], 0, 0, 0);
                acc[1][ct] = __builtin_amdgcn_mfma_f32_16x16x32_bf16(a[1], b, acc[1][ct], 0, 0, 0);
            }
        }
#pragma unroll
        for (int rt = 0; rt < 2; rt++)
#pragma unroll
            for (int i = 0; i < 4; i++) {
                int r = r0 + rt * 16 + qd * 4 + i;
                if (r < n) {
#pragma unroll
                    for (int ct = 0; ct < 8; ct++)
                        outb[(size_t)r * 128 + ct * 16 + m] = (unsigned short)f2bf(acc[rt][ct][i]);
                }
            }
    }

    if (STATS) {
        __shared__ float ls[4][128], lq[4][128];
#pragma unroll
        for (int ct = 0; ct < 8; ct++) {
            float s = 0.f, q = 0.f;
#pragma unroll
            for (int rt = 0; rt < 2; rt++)
#pragma unroll
                for (int i = 0; i < 4; i++) {
                    float v = acc[rt][ct][i];
                    s += v;
                    q += v * v;
                }
            s += __shfl_xor(s, 16, 64);
            s += __shfl_xor(s, 32, 64);
            q += __shfl_xor(q, 16, 64);
            q += __shfl_xor(q, 32, 64);
            if (qd == 0) {
                ls[wv][ct * 16 + m] = s;
                lq[wv][ct * 16 + m] = q;
            }
        }
        __syncthreads();
        int t = threadIdx.x;
        if (t < 128) {
            atomicAdd(&sums[t], ls[0][t] + ls[1][t] + ls[2][t] + ls[3][t]);
        } else {
            int c = t - 128;
            atomicAdd(&sums[128 + c], lq[0][c] + lq[1][c] + lq[2][c] + lq[3][c]);
        }
    }
}

// GEMV, bf16 input, fused norm: out[n] = relu(hb[n,128]*S+T) @ W[128]
__global__ void gemv_norm_bf(const unsigned short* __restrict__ hb, const float* __restrict__ W,
                             const float* __restrict__ ss, float* __restrict__ out, int n) {
    int gid = blockIdx.x * blockDim.x + threadIdx.x;
    int wid = gid >> 6, lane = gid & 63;
    int nw = (gridDim.x * blockDim.x) >> 6;
    int c = lane * 2;
    float w0 = W[c], w1 = W[c + 1];
    float s0 = ss[c], s1 = ss[c + 1];
    float t0 = ss[128 + c], t1 = ss[128 + c + 1];
    for (int r = wid; r < n; r += nw) {
        ushort2 u = ((const ushort2*)(hb + (size_t)r * 128))[lane];
        float a = fmaxf(fmaf(bf2f(u.x), s0, t0), 0.f);
        float b = fmaxf(fmaf(bf2f(u.y), s1, t1), 0.f);
        float v = fmaf(a, w0, b * w1);
#pragma unroll
        for (int off = 32; off > 0; off >>= 1) v += __shfl_down(v, off, 64);
        if (lane == 0) out[r] = v;
    }
}

// ================= CSR gather aggregate, bf16 in/out, fused self-loop + stats ============
// 8 groups x 32 lanes; group handles 8 consecutive nodes; 64 nodes/block.
__global__ __launch_bounds__(256) void agg128_bf(const unsigned short* __restrict__ tmp,
                                                 const int* __restrict__ rowptr,
                                                 const int* __restrict__ esrc,
                                                 const float* __restrict__ ewt,
                                                 const float* __restrict__ dinv,
                                                 unsigned short* __restrict__ agg,
                                                 float* __restrict__ sums, int n) {
    __shared__ float ls[8][128], lq[8][128];
    int g = threadIdx.x >> 5;
    int c4 = threadIdx.x & 31;
    float4 s4 = make_float4(0.f, 0.f, 0.f, 0.f);
    float4 q4 = make_float4(0.f, 0.f, 0.f, 0.f);
    int base = blockIdx.x * 64 + g * 8;
    for (int i = 0; i < 8; i++) {
        int node = base + i;
        if (node < n) {
            float di = dinv[node];
            float d2 = di * di;
            ushort4 t = ((const ushort4*)tmp)[(size_t)node * 32 + c4];
            float4 acc;
            acc.x = bf2f(t.x) * d2;
            acc.y = bf2f(t.y) * d2;
            acc.z = bf2f(t.z) * d2;
            acc.w = bf2f(t.w) * d2;
            int j = rowptr[node], end = rowptr[node + 1];
            for (; j + 4 <= end; j += 4) {
                int sA = esrc[j], sB = esrc[j + 1], sC = esrc[j + 2], sD = esrc[j + 3];
                float wA = ewt[j], wB = ewt[j + 1], wC = ewt[j + 2], wD = ewt[j + 3];
                ushort4 vA = ((const ushort4*)tmp)[(size_t)sA * 32 + c4];
                ushort4 vB = ((const ushort4*)tmp)[(size_t)sB * 32 + c4];
                ushort4 vC = ((const ushort4*)tmp)[(size_t)sC * 32 + c4];
                ushort4 vD = ((const ushort4*)tmp)[(size_t)sD * 32 + c4];
                acc.x = fmaf(bf2f(vA.x), wA, acc.x); acc.y = fmaf(bf2f(vA.y), wA, acc.y);
                acc.z = fmaf(bf2f(vA.z), wA, acc.z); acc.w = fmaf(bf2f(vA.w), wA, acc.w);
                acc.x = fmaf(bf2f(vB.x), wB, acc.x); acc.y = fmaf(bf2f(vB.y), wB, acc.y);
                acc.z = fmaf(bf2f(vB.z), wB, acc.z); acc.w = fmaf(bf2f(vB.w), wB, acc.w);
                acc.x = fmaf(bf2f(vC.x), wC, acc.x); acc.y = fmaf(bf2f(vC.y), wC, acc.y);
                acc.z = fmaf(bf2f(vC.z), wC, acc.z); acc.w = fmaf(bf2f(vC.w), wC, acc.w);
                acc.x = fmaf(bf2f(vD.x), wD, acc.x); acc.y = fmaf(bf2f(vD.y), wD, acc.y);
                acc.z = fmaf(bf2f(vD.z), wD, acc.z); acc.w = fmaf(bf2f(vD.w), wD, acc.w);
            }
            for (; j < end; j++) {
                int s = esrc[j];
                float w = ewt[j];
                ushort4 v = ((const ushort4*)tmp)[(size_t)s * 32 + c4];
                acc.x = fmaf(bf2f(v.x), w, acc.x); acc.y = fmaf(bf2f(v.y), w, acc.y);
                acc.z = fmaf(bf2f(v.z), w, acc.z); acc.w = fmaf(bf2f(v.w), w, acc.w);
            }
            ushort4 o;
            o.x = (unsigned short)f2bf(acc.x);
            o.y = (unsigned short)f2bf(acc.y);
            o.z = (unsigned short)f2bf(acc.z);
            o.w = (unsigned short)f2bf(acc.w);
            ((ushort4*)agg)[(size_t)node * 32 + c4] = o;
            s4.x += acc.x; s4.y += acc.y; s4.z += acc.z; s4.w += acc.w;
            q4.x = fmaf(acc.x, acc.x, q4.x); q4.y = fmaf(acc.y, acc.y, q4.y);
            q4.z = fmaf(acc.z, acc.z, q4.z); q4.w = fmaf(acc.w, acc.w, q4.w);
        }
    }
    ls[g][4 * c4 + 0] = s4.x; ls[g][4 * c4 + 1] = s4.y;
    ls[g][4 * c4 + 2] = s4.z; ls[g][4 * c4 + 3] = s4.w;
    lq[g][4 * c4 + 0] = q4.x; lq[g][4 * c4 + 1] = q4.y;
    lq[g][4 * c4 + 2] = q4.z; lq[g][4 * c4 + 3] = q4.w;
    __syncthreads();
    int t = threadIdx.x;
    if (t < 128) {
        float s = ls[0][t] + ls[1][t] + ls[2][t] + ls[3][t] +
                  ls[4][t] + ls[5][t] + ls[6][t] + ls[7][t];
        atomicAdd(&sums[t], s);
    } else {
        int c = t - 128;
        float q = lq[0][c] + lq[1][c] + lq[2][c] + lq[3][c] +
                  lq[4][c] + lq[5][c] + lq[6][c] + lq[7][c];
        atomicAdd(&sums[128 + c], q);
    }
}

// 32-channel bf16 gather (layer-1 input space)
__global__ __launch_bounds__(256) void agg32_bf(const unsigned short* __restrict__ xb,
                                                const int* __restrict__ rowptr,
                                                const int* __restrict__ esrc,
                                                const float* __restrict__ ewt,
                                                const float* __restrict__ dinv,
                                                unsigned short* __restrict__ xab, int n) {
    int node = (blockIdx.x << 3) + (threadIdx.x >> 5);
    if (node >= n) return;
    int c = threadIdx.x & 31;
    float di = dinv[node];
    float acc = bf2f(xb[((size_t)node << 5) + c]) * di * di;
    int j = rowptr[node], end = rowptr[node + 1];
    for (; j + 4 <= end; j += 4) {
        int s0 = esrc[j], s1 = esrc[j + 1], s2 = esrc[j + 2], s3 = esrc[j + 3];
        float w0 = ewt[j], w1 = ewt[j + 1], w2 = ewt[j + 2], w3 = ewt[j + 3];
        float v0 = bf2f(xb[((size_t)s0 << 5) + c]);
        float v1 = bf2f(xb[((size_t)s1 << 5) + c]);
        float v2 = bf2f(xb[((size_t)s2 << 5) + c]);
        float v3 = bf2f(xb[((size_t)s3 << 5) + c]);
        acc = fmaf(v0, w0, acc);
        acc = fmaf(v1, w1, acc);
        acc = fmaf(v2, w2, acc);
        acc = fmaf(v3, w3, acc);
    }
    for (; j < end; j++) {
        acc = fmaf(bf2f(xb[((size_t)esrc[j] << 5) + c]), ewt[j], acc);
    }
    xab[((size_t)node << 5) + c] = (unsigned short)f2bf(acc);
}

__global__ void agg1_csr(const float* __restrict__ tmp, const int* __restrict__ rowptr,
                         const int* __restrict__ esrc, const float* __restrict__ ewt,
                         const float* __restrict__ dinv, float* __restrict__ out, int n) {
    int i = blockIdx.x * blockDim.x + threadIdx.x;
    if (i >= n) return;
    float di = dinv[i];
    float acc = tmp[i] * di * di;
    int beg = rowptr[i], end = rowptr[i + 1];
    for (int j = beg; j < end; j++) {
        acc = fmaf(tmp[esrc[j]], ewt[j], acc);
    }
    out[i] = acc;
}

__global__ void stats1_kernel(const float* __restrict__ a, float* __restrict__ sums, int n) {
    int gid = blockIdx.x * blockDim.x + threadIdx.x;
    float s = 0.f, q = 0.f;
    for (int i = gid; i < n; i += gridDim.x * blockDim.x) {
        float v = a[i];
        s += v;
        q += v * v;
    }
#pragma unroll
    for (int off = 32; off > 0; off >>= 1) {
        s += __shfl_down(s, off, 64);
        q += __shfl_down(q, off, 64);
    }
    if ((threadIdx.x & 63) == 0) {
        atomicAdd(&sums[0], s);
        atomicAdd(&sums[1], q);
    }
}

// ================= finalize: fused BN->IN->LN =================
template <int C>
__global__ void finalize_kernel(const float* __restrict__ sums, const float* __restrict__ g,
                                const float* __restrict__ lw, const float* __restrict__ lb,
                                float* __restrict__ ss, int n) {
    __shared__ float vt2[C];
    int c = threadIdx.x;
    float m = sums[c] / n;
    float v = sums[C + c] / n - m * m;
    v = v < 0.f ? 0.f : v;
    float gc = g[c];
    float bs = rsqrtf(v + EPS) * gc;
    float vz = v * bs * bs;
    float t = bs * rsqrtf(vz + EPS);
    vt2[c] = v * t * t;
    __syncthreads();
    if (c == 0) {
        float gv = 0.f;
        for (int i = 0; i < C; i++) gv += vt2[i];
        vt2[0] = gv / C;
    }
    __syncthreads();
    float GV = vt2[0];
    float S = t * rsqrtf(GV + EPS) * lw[c];
    ss[c] = S;
    ss[C + c] = lb[c] - m * S;
}

template <int C, bool RELU>
__global__ void apply_kernel(const float* __restrict__ ss, const float* a, float* out, int n) {
    int i = blockIdx.x * blockDim.x + threadIdx.x;
    if (i < n * C) {
        int c = (C == 1) ? 0 : (i & (C - 1));
        float y = fmaf(a[i], ss[c], ss[C + c]);
        if (RELU) y = y > 0.f ? y : 0.f;
        out[i] = y;
    }
}

extern "C" void kernel_launch(void* const* d_in, const int* in_sizes, int n_in,
                              void* d_out, int out_size, void* d_ws, size_t ws_size,
                              hipStream_t stream) {
    const float* x = (const float*)d_in[0];
    const int* ei = (const int*)d_in[1];
    int n = in_sizes[0] / 32;
    int E = in_sizes[1] / 2;
    const int* src = ei;
    const int* dstp = ei + E;
    const float* W1 = (const float*)d_in[2];
    const float* g1 = (const float*)d_in[4];
    const float* lw1 = (const float*)d_in[6];
    const float* lb1 = (const float*)d_in[7];
    const float* W2 = (const float*)d_in[8];
    const float* g2 = (const float*)d_in[10];
    const float* lw2 = (const float*)d_in[12];
    const float* lb2 = (const float*)d_in[13];
    const float* W3 = (const float*)d_in[14];
    const float* g3 = (const float*)d_in[16];
    const float* lw3 = (const float*)d_in[18];
    const float* lb3 = (const float*)d_in[19];
    float* out = (float*)d_out;

    // workspace layout (16B-aligned chunks)
    char* p = (char*)d_ws;
    int* counts = (int*)p;             p += (size_t)n * 4;
    int* rowptr = (int*)p;             p += (size_t)(n + 4) * 4;
    int* aux = (int*)p;                p += 128 * 4;
    int* esrc = (int*)p;               p += (size_t)E * 4;
    float* ewt = (float*)p;            p += (size_t)E * 4;
    float* dinv = (float*)p;           p += (size_t)n * 4;
    unsigned short* Wt1 = (unsigned short*)p;  p += 128 * 32 * 2;
    unsigned short* Wt2 = (unsigned short*)p;  p += 128 * 128 * 2;
    unsigned short* xb = (unsigned short*)p;   p += (size_t)n * 32 * 2;
    unsigned short* xa = (unsigned short*)p;   p += (size_t)n * 32 * 2;
    unsigned short* h1 = (unsigned short*)p;   p += (size_t)n * 128 * 2;
    unsigned short* t2 = (unsigned short*)p;   p += (size_t)n * 128 * 2;
    unsigned short* a2 = (unsigned short*)p;   p += (size_t)n * 128 * 2;
    float* t3 = (float*)p;             p += (size_t)n * 4;
    float* a3 = (float*)p;             p += (size_t)n * 4;
    float* sums1 = (float*)p;          p += 256 * 4;
    float* sums2 = (float*)p;          p += 256 * 4;
    float* sums3 = (float*)p;          p += 4 * 4;
    float* ss1 = (float*)p;            p += 256 * 4;
    float* ss2 = (float*)p;            p += 256 * 4;
    float* ss3 = (float*)p;            p += 4 * 4;

    int B = (n + 1023) / 1024;

    // ---- CSR build + prep ----
    hipMemsetAsync(counts, 0, (size_t)n * 4, stream);
    hipMemsetAsync(sums1, 0, 516 * 4, stream);
    hist_kernel<<<(E + 255) / 256, 256, 0, stream>>>(dstp, E, counts);
    dinv_kernel<<<(n + 255) / 256, 256, 0, stream>>>(counts, dinv, n);
    scan_part<<<B, 1024, 0, stream>>>(counts, rowptr, aux, n);
    scan_aux<<<1, 128, 0, stream>>>(aux, B);
    scan_add<<<(n + 255) / 256, 256, 0, stream>>>(rowptr, aux, n, E);
    hipMemcpyAsync(counts, rowptr, (size_t)n * 4, hipMemcpyDeviceToDevice, stream);
    fill_kernel<<<(E + 255) / 256, 256, 0, stream>>>(src, dstp, E, counts, dinv, esrc, ewt);
    wt_bf16_kernel<<<(32 * 128 + 255) / 256, 256, 0, stream>>>(W1, Wt1, 32, 128);
    wt_bf16_kernel<<<(128 * 128 + 255) / 256, 256, 0, stream>>>(W2, Wt2, 128, 128);
    cvt_bf16_kernel<<<(n * 8 + 255) / 256, 256, 0, stream>>>(x, xb, n * 8);

    int mblk = ((n + 31) / 32 + 3) / 4;  // 4 waves/block, 32-row strip per wave
    int nblk8 = (n + 7) / 8;
    int nblk64 = (n + 63) / 64;

    // ---- layer 1: agg(x) in 32-dim, then MFMA GEMM 32->128 with fused stats ----
    agg32_bf<<<nblk8, 256, 0, stream>>>(xb, rowptr, esrc, ewt, dinv, xa, n);
    gemm_mfma<32, false, true><<<mblk, 256, 0, stream>>>(xa, Wt1, nullptr, h1, sums1, n);
    finalize_kernel<128><<<1, 128, 0, stream>>>(sums1, g1, lw1, lb1, ss1, n);

    // ---- layer 2: MFMA GEMM 128->128 (norm fused on load), agg with fused stats ----
    gemm_mfma<128, true, false><<<mblk, 256, 0, stream>>>(h1, Wt2, ss1, t2, nullptr, n);
    agg128_bf<<<nblk64, 256, 0, stream>>>(t2, rowptr, esrc, ewt, dinv, a2, sums2, n);
    finalize_kernel<128><<<1, 128, 0, stream>>>(sums2, g2, lw2, lb2, ss2, n);

    // ---- layer 3: gemv (norm fused), agg, norm, out ----
    gemv_norm_bf<<<1024, 256, 0, stream>>>(a2, W3, ss2, t3, n);
    agg1_csr<<<(n + 255) / 256, 256, 0, stream>>>(t3, rowptr, esrc, ewt, dinv, a3, n);
    stats1_kernel<<<256, 256, 0, stream>>>(a3, sums3, n);
    finalize_kernel<1><<<1, 1, 0, stream>>>(sums3, g3, lw3, lb3, ss3, n);
    apply_kernel<1, false><<<(n + 255) / 256, 256, 0, stream>>>(ss3, a3, out, n);
}